// Round 2
// baseline (7512.170 us; speedup 1.0000x reference)
//
#include <hip/hip_runtime.h>
#include <cmath>

#define BTOT 32768
#define R 8

// output offsets (floats)
#define OSIG 0
#define OEXC (BTOT*40)
#define OPREV (OEXC + BTOT*256)
#define OH1 (OPREV + BTOT*256)
#define OH2 (OH1 + BTOT*160)
#define OH3 (OH2 + BTOT*128)
#define ONS4 (OH3 + BTOT*128)

__device__ __forceinline__ float sigm(float x){ return 1.0f/(1.0f+__expf(-x)); }
__device__ __forceinline__ float tanh_f(float x){
    float e = __expf(2.0f*x);
    return 1.0f - 2.0f/(e+1.0f);
}

// dot of n4*4 elements: w from global (float4), x from LDS (float4)
__device__ __forceinline__ float seg_dot(const float* __restrict__ w, const float* x, int n4){
    float acc = 0.f;
    #pragma unroll 4
    for (int i=0;i<n4;++i){
        float4 wv = reinterpret_cast<const float4*>(w)[i];
        float4 xv = reinterpret_cast<const float4*>(x)[i];
        acc = fmaf(wv.x, xv.x, acc);
        acc = fmaf(wv.y, xv.y, acc);
        acc = fmaf(wv.z, xv.z, acc);
        acc = fmaf(wv.w, xv.w, acc);
    }
    return acc;
}

extern "C" __global__ __launch_bounds__(256, 2)
void fargan_kernel(
    const float* __restrict__ cond, const float* __restrict__ prev_pred,
    const float* __restrict__ exc_mem, const float* __restrict__ period,
    const float* __restrict__ s1, const float* __restrict__ s2,
    const float* __restrict__ s3, const float* __restrict__ s4,
    const float* __restrict__ w_gain, const float* __restrict__ b_gain,
    const float* __restrict__ w_fwc0, const float* __restrict__ w_fwc0_glu,
    const float* __restrict__ wih1, const float* __restrict__ whh1, const float* __restrict__ wglu1,
    const float* __restrict__ wih2, const float* __restrict__ whh2, const float* __restrict__ wglu2,
    const float* __restrict__ wih3, const float* __restrict__ whh3, const float* __restrict__ wglu3,
    const float* __restrict__ w_skip, const float* __restrict__ w_skip_glu,
    const float* __restrict__ w_sig, const float* __restrict__ w_pg, const float* __restrict__ b_pg,
    float* __restrict__ out)
{
    __shared__ __align__(16) float arena[15536];
    const int tid = threadIdx.x;
    const int r = tid >> 5;      // row within block (0..7)
    const int j = tid & 31;      // lane within 32-thread row group
    const int row = blockIdx.x * R + r;

    float* TMP   = arena + 0     + r*164;   // [cond(80) | pred_n(44) | prev(40)]
    float* S4    = arena + 1312  + r*164;
    float* FWRAW = arena + 2624  + r*192;   // tanh(xcat@w_fwc0)
    float* FWC0  = arena + 4160  + r*192;   // fwc0_out
    float* PGA   = arena + 5696  + r*4;
    float* PF    = arena + 5728  + r*40;    // pg_k * fpitch
    float* HST   = arena + 6048  + r*160;   // GRU h state
    float* RZ    = arena + 7328  + r*320;   // r,z gates
    float* HB    = arena + 9888  + r*160;   // h out / glu in
    float* G1    = arena + 11168 + r*160;
    float* G2    = arena + 12448 + r*128;
    float* G3    = arena + 13472 + r*128;
    float* SK    = arena + 14496 + r*128;   // tanh(skip)
    float* SK2   = arena + 1312  + r*128;   // final sk, overlays S4 (dead after fwc0)
    float* GAINA = arena + 15520;           // [8]
    // ---- Stage A: gain, pred interpolation, tmp build, passthrough copies ----
    const float* exc_row = exc_mem + row*256;

    float a = 0.f;
    for (int i=j;i<80;i+=32) a += cond[row*80+i]*w_gain[i];
    a += __shfl_xor(a,16); a += __shfl_xor(a,8); a += __shfl_xor(a,4);
    a += __shfl_xor(a,2);  a += __shfl_xor(a,1);
    float g = 0.2f + 0.8f*sigm(a + b_gain[0]);
    if (!(g==g)) g = 1.0f;                       // nan_to_num(nan=1.0)
    g = fminf(fmaxf(g, 0.001f), 20.0f);          // clip
    float inv = 1.0f/(1e-5f+g);
    if (j==0) GAINA[r]=g;

    float p = period[row];
    p = (fabsf(p) <= 3.0e38f) ? p : 128.0f;      // nan/inf -> 128
    p = fminf(fmaxf(p,32.0f),255.0f);

    for (int i=j;i<80;i+=32) TMP[i] = cond[row*80+i];

    for (int e=j;e<44;e+=32){
        float idxf = 256.0f - p + (float)e - 2.0f;
        float idx0 = floorf(idxf);
        float alpha = fminf(fmaxf(idxf-idx0,0.f),1.f);
        int i0 = (int)fminf(fmaxf(idx0,0.f),255.f);
        int i1 = (int)fminf(fmaxf(idx0+1.0f,0.f),255.f);
        float v0 = exc_row[i0], v1 = exc_row[i1];
        float pr = (1.f-alpha)*v0 + alpha*v1;
        TMP[80+e] = pr*inv;                       // pred_n
        if (e>=2 && e<42) out[OPREV + row*256 + 216 + (e-2)] = pr;
    }
    for (int i=j;i<40;i+=32)  TMP[124+i] = exc_row[216+i]*inv;   // prev
    for (int i=j;i<164;i+=32) S4[i] = s4[row*164+i];
    for (int i=j;i<216;i+=32){
        out[OPREV + row*256 + i] = prev_pred[row*256 + 40 + i];
        out[OEXC  + row*256 + i] = exc_row[40+i];
    }
    __syncthreads();

    // new_s4 = tmp
    for (int i=j;i<164;i+=32) out[ONS4 + row*164 + i] = TMP[i];

    // ---- Stage B: fwc0 ---- xcat = [s4(164), tmp(164)], K=328, O=192
    float fw[6];
    #pragma unroll
    for (int u=0;u<6;++u){
        int o = j + 32*u;
        const float* wr = w_fwc0 + o*328;
        float acc = seg_dot(wr, S4, 41) + seg_dot(wr+164, TMP, 41);
        fw[u] = tanh_f(acc);
        FWRAW[o] = fw[u];
    }
    __syncthreads();
    #pragma unroll
    for (int u=0;u<6;++u){
        int o = j + 32*u;
        FWC0[o] = fw[u]*sigm(seg_dot(w_fwc0_glu + o*192, FWRAW, 48));
    }
    __syncthreads();

    // ---- pitch gain (O=4, K=192) + GRU1 prep ----
    if (j<4) PGA[j] = sigm(seg_dot(w_pg + j*192, FWC0, 48) + b_pg[j]);
    for (int i=j;i<160;i+=32) HST[i] = s1[row*160+i];
    __syncthreads();
    for (int i=j;i<40;i+=32) PF[i] = PGA[0]*TMP[82+i];   // fpitch = pred_n[2:42]
    __syncthreads();

    // ---- GRU1: x=[fwc0(192),pf(40),prev(40)] K=272, h=160, O=480 ----
    #pragma unroll
    for (int u=0;u<10;++u){    // r,z (o<320)
        int o = j + 32*u;
        const float* wr = wih1 + o*272;
        float acc = seg_dot(wr, FWC0, 48) + seg_dot(wr+192, PF, 10)
                  + seg_dot(wr+232, TMP+124, 10) + seg_dot(whh1 + o*160, HST, 40);
        RZ[o] = sigm(acc);
    }
    __syncthreads();
    #pragma unroll
    for (int u=0;u<5;++u){     // n, h1
        int o = j + 32*u;
        const float* wr = wih1 + (320+o)*272;
        float gx = seg_dot(wr, FWC0, 48) + seg_dot(wr+192, PF, 10) + seg_dot(wr+232, TMP+124, 10);
        float gh = seg_dot(whh1 + (320+o)*160, HST, 40);
        float n = tanh_f(gx + RZ[o]*gh);
        float zz = RZ[160+o];
        float h = (1.f-zz)*n + zz*HST[o];
        HB[o] = h;
        out[OH1 + row*160 + o] = h;
    }
    __syncthreads();
    #pragma unroll
    for (int u=0;u<5;++u){     // glu1
        int o = j+32*u;
        G1[o] = HB[o]*sigm(seg_dot(wglu1 + o*160, HB, 40));
    }
    __syncthreads();
    for (int i=j;i<128;i+=32) HST[i] = s2[row*128+i];
    for (int i=j;i<40;i+=32)  PF[i] = PGA[1]*TMP[82+i];
    __syncthreads();

    // ---- GRU2: x=[g1(160),pf(40),prev(40)] K=240, h=128, O=384 ----
    #pragma unroll
    for (int u=0;u<8;++u){
        int o=j+32*u;
        const float* wr = wih2 + o*240;
        float acc = seg_dot(wr, G1, 40) + seg_dot(wr+160, PF, 10)
                  + seg_dot(wr+200, TMP+124, 10) + seg_dot(whh2 + o*128, HST, 32);
        RZ[o] = sigm(acc);
    }
    __syncthreads();
    #pragma unroll
    for (int u=0;u<4;++u){
        int o=j+32*u;
        const float* wr = wih2 + (256+o)*240;
        float gx = seg_dot(wr,G1,40)+seg_dot(wr+160,PF,10)+seg_dot(wr+200,TMP+124,10);
        float gh = seg_dot(whh2 + (256+o)*128, HST, 32);
        float n = tanh_f(gx + RZ[o]*gh);
        float zz = RZ[128+o];
        float h = (1.f-zz)*n + zz*HST[o];
        HB[o]=h; out[OH2 + row*128+o]=h;
    }
    __syncthreads();
    #pragma unroll
    for (int u=0;u<4;++u){ int o=j+32*u; G2[o]=HB[o]*sigm(seg_dot(wglu2+o*128,HB,32)); }
    __syncthreads();
    for (int i=j;i<128;i+=32) HST[i]=s3[row*128+i];
    for (int i=j;i<40;i+=32)  PF[i]=PGA[2]*TMP[82+i];
    __syncthreads();

    // ---- GRU3: x=[g2(128),pf(40),prev(40)] K=208, h=128, O=384 ----
    #pragma unroll
    for (int u=0;u<8;++u){
        int o=j+32*u;
        const float* wr=wih3+o*208;
        float acc=seg_dot(wr,G2,32)+seg_dot(wr+128,PF,10)
                 +seg_dot(wr+168,TMP+124,10)+seg_dot(whh3+o*128,HST,32);
        RZ[o]=sigm(acc);
    }
    __syncthreads();
    #pragma unroll
    for (int u=0;u<4;++u){
        int o=j+32*u;
        const float* wr=wih3+(256+o)*208;
        float gx=seg_dot(wr,G2,32)+seg_dot(wr+128,PF,10)+seg_dot(wr+168,TMP+124,10);
        float gh=seg_dot(whh3+(256+o)*128,HST,32);
        float n=tanh_f(gx+RZ[o]*gh);
        float zz=RZ[128+o];
        float h=(1.f-zz)*n+zz*HST[o];
        HB[o]=h; out[OH3+row*128+o]=h;
    }
    __syncthreads();
    #pragma unroll
    for (int u=0;u<4;++u){ int o=j+32*u; G3[o]=HB[o]*sigm(seg_dot(wglu3+o*128,HB,32)); }
    __syncthreads();
    for (int i=j;i<40;i+=32) PF[i]=PGA[3]*TMP[82+i];
    __syncthreads();

    // ---- skip: K=688 = [g1(160),g2(128),g3(128),fwc0(192),pf(40),prev(40)], O=128 ----
    float skv[4];
    #pragma unroll
    for (int u=0;u<4;++u){
        int o=j+32*u;
        const float* wr=w_skip+o*688;
        float acc=seg_dot(wr,G1,40)+seg_dot(wr+160,G2,32)+seg_dot(wr+288,G3,32)
                 +seg_dot(wr+416,FWC0,48)+seg_dot(wr+608,PF,10)+seg_dot(wr+648,TMP+124,10);
        skv[u]=tanh_f(acc); SK[o]=skv[u];
    }
    __syncthreads();
    #pragma unroll
    for (int u=0;u<4;++u){
        int o=j+32*u;
        SK2[o]=skv[u]*sigm(seg_dot(w_skip_glu+o*128,SK,32));
    }
    __syncthreads();

    // ---- sig: O=40, K=128; write sig_out and exc_mem_new tail ----
    for (int o=j;o<40;o+=32){
        float s=tanh_f(seg_dot(w_sig+o*128,SK2,32))*GAINA[r];
        out[OSIG + row*40 + o] = s;
        out[OEXC + row*256 + 216 + o] = s;
    }
}

extern "C" void kernel_launch(void* const* d_in, const int* in_sizes, int n_in,
                              void* d_out, int out_size, void* d_ws, size_t ws_size,
                              hipStream_t stream) {
    const float* cond      = (const float*)d_in[0];
    const float* prev_pred = (const float*)d_in[1];
    const float* exc_mem   = (const float*)d_in[2];
    const float* period    = (const float*)d_in[3];
    const float* s1        = (const float*)d_in[4];
    const float* s2        = (const float*)d_in[5];
    const float* s3        = (const float*)d_in[6];
    const float* s4        = (const float*)d_in[7];
    const float* w_gain    = (const float*)d_in[8];
    const float* b_gain    = (const float*)d_in[9];
    const float* w_fwc0    = (const float*)d_in[10];
    const float* w_fwc0_glu= (const float*)d_in[11];
    const float* wih1      = (const float*)d_in[12];
    const float* whh1      = (const float*)d_in[13];
    const float* wglu1     = (const float*)d_in[14];
    const float* wih2      = (const float*)d_in[15];
    const float* whh2      = (const float*)d_in[16];
    const float* wglu2     = (const float*)d_in[17];
    const float* wih3      = (const float*)d_in[18];
    const float* whh3      = (const float*)d_in[19];
    const float* wglu3     = (const float*)d_in[20];
    const float* w_skip    = (const float*)d_in[21];
    const float* w_skip_glu= (const float*)d_in[22];
    const float* w_sig     = (const float*)d_in[23];
    const float* w_pg      = (const float*)d_in[24];
    const float* b_pg      = (const float*)d_in[25];
    float* out = (float*)d_out;

    dim3 grid(BTOT / R);
    dim3 block(256);
    hipLaunchKernelGGL(fargan_kernel, grid, block, 0, stream,
        cond, prev_pred, exc_mem, period, s1, s2, s3, s4,
        w_gain, b_gain, w_fwc0, w_fwc0_glu,
        wih1, whh1, wglu1, wih2, whh2, wglu2, wih3, whh3, wglu3,
        w_skip, w_skip_glu, w_sig, w_pg, b_pg, out);
}

// Round 3
// 504.076 us; speedup vs baseline: 14.9028x; 14.9028x over previous
//
#include <hip/hip_runtime.h>
#include <cstdint>
#include <cmath>

#define BTOT 32768L
#define OSIG 0L
#define OEXC (BTOT*40L)
#define OPREV (OEXC + BTOT*256L)
#define OH1 (OPREV + BTOT*256L)
#define OH2 (OH1 + BTOT*160L)
#define OH3 (OH2 + BTOT*128L)
#define ONS4 (OH3 + BTOT*128L)

typedef __attribute__((ext_vector_type(8))) short short8;
typedef __attribute__((ext_vector_type(4))) float f32x4;

// ws layout (bf16 elems), weights padded to [Npad][KP], KP,Npad multiples of 64(=N)/32(=K pad to 64)
#define W_F0     0L        // [192][384]
#define W_F0G    73728L    // [192][192]
#define W_IH1RZ  110592L   // [320][320]
#define W_IH1N   212992L   // [192][320]
#define W_HH1RZ  274432L   // [320][192]
#define W_HH1N   335872L   // [192][192]
#define W_GLU1   372736L   // [192][192]
#define W_IH2RZ  409600L   // [256][256]
#define W_IH2N   475136L   // [128][256]
#define W_HH2RZ  507904L   // [256][128]
#define W_HH2N   540672L   // [128][128]
#define W_GLU2   557056L   // [128][128]
#define W_IH3RZ  573440L   // [256][256]
#define W_IH3N   638976L   // [128][256]
#define W_HH3RZ  671744L   // [256][128]
#define W_HH3N   704512L   // [128][128]
#define W_GLU3   720896L   // [128][128]
#define W_SKIP   737280L   // [128][704]
#define W_SKIPG  827392L   // [128][128]
#define W_SIG    843776L   // [64][128]

__device__ __forceinline__ float sigm(float x){ return 1.0f/(1.0f+__expf(-x)); }
__device__ __forceinline__ float tanh_f(float x){
    float e = __expf(2.0f*x);
    return 1.0f - 2.0f/(e+1.0f);
}
__device__ __forceinline__ uint16_t f2bf(float x){
    union { float f; uint32_t u; } v; v.f = x;
    uint32_t r = v.u + 0x7FFFu + ((v.u>>16)&1u);
    return (uint16_t)(r>>16);
}
__device__ __forceinline__ float bf2f(uint16_t h){
    union { float f; uint32_t u; } v; v.u = ((uint32_t)h)<<16;
    return v.f;
}

// ---------------- prep: fp32 weights -> padded bf16 in ws ----------------
struct PrepArgs { const float* s[14]; };

__global__ __launch_bounds__(64) void prep_kernel(PrepArgs pa, uint16_t* dst){
    // srcidx, rowoff, N, K, Npad, KP, dstoff
    static const int J[20][7] = {
        {0,0,192,328,192,384,0},
        {1,0,192,192,192,192,73728},
        {2,0,320,272,320,320,110592},
        {2,320,160,272,192,320,212992},
        {3,0,320,160,320,192,274432},
        {3,320,160,160,192,192,335872},
        {4,0,160,160,192,192,372736},
        {5,0,256,240,256,256,409600},
        {5,256,128,240,128,256,475136},
        {6,0,256,128,256,128,507904},
        {6,256,128,128,128,128,540672},
        {7,0,128,128,128,128,557056},
        {8,0,256,208,256,256,573440},
        {8,256,128,208,128,256,638976},
        {9,0,256,128,256,128,671744},
        {9,256,128,128,128,128,704512},
        {10,0,128,128,128,128,720896},
        {11,0,128,688,128,704,737280},
        {12,0,128,128,128,128,827392},
        {13,0,40,128,64,128,843776},
    };
    int row = blockIdx.x;
    int j = 0;
    while (row >= J[j][4]) { row -= J[j][4]; ++j; }
    const float* src = pa.s[J[j][0]];
    const int ro = J[j][1], N = J[j][2], K = J[j][3], KP = J[j][5];
    uint16_t* d = dst + (long)J[j][6] + (long)row*KP;
    for (int k = threadIdx.x; k < KP; k += 64){
        float v = (row < N && k < K) ? src[(long)(ro+row)*K + k] : 0.0f;
        d[k] = f2bf(v);
    }
}

// ---------------- wave GEMM: 16 rows x (CNT tiles of 16 cols), K = KP ----------------
// A: LDS bf16 [16][P] (P%64==8 elems -> conflict-optimal ds_read_b128)
// B: global bf16 [Npad][KP] (row n = weight row n, k-contiguous)
// C(m,n): m = (lane>>4)*4+q, n = tile*16 + (lane&15)
template<int CNT>
__device__ __forceinline__ void wgemm(f32x4* acc, const uint16_t* __restrict__ Bw, int KP,
                                      const uint16_t* A, int P, int wv, int r16, int g)
{
    const uint16_t* ap = A + r16*P + g*8;
    const uint16_t* bp[CNT];
    #pragma unroll
    for (int i = 0; i < CNT; ++i)
        bp[i] = Bw + (size_t)((wv + 4*i)*16 + r16)*KP + g*8;
    const int ks = KP >> 5;
    #pragma unroll 2
    for (int s = 0; s < ks; ++s){
        short8 af = *(const short8*)(ap + s*32);
        #pragma unroll
        for (int i = 0; i < CNT; ++i){
            short8 bf = *(const short8*)(bp[i] + s*32);
            acc[i] = __builtin_amdgcn_mfma_f32_16x16x32_bf16(af, bf, acc[i], 0, 0, 0);
        }
    }
}

// ---------------- GRU stage ----------------
// XBUF [16][328] (x-cat, KXP valid), HST [16][200] (h, KHP valid), RZ [16][328], HB [16][200]
template<int H, int RZT, int NT>
__device__ __forceinline__ void gru_stage(
    const uint16_t* wihrz, const uint16_t* whhrz, const uint16_t* wihn, const uint16_t* whhn,
    const uint16_t* wglu, int KXP, int KHP, int KGP, int HP,
    uint16_t* XBUFb, uint16_t* RZb, uint16_t* HSTb, uint16_t* HBb,
    const float* __restrict__ sglob, float* __restrict__ out, long outbase,
    uint16_t* SKIPB, int gslot, bool toXbuf,
    int row0, int wv, int r16, int g)
{
    f32x4 zero4 = {0.f,0.f,0.f,0.f};
    // r,z gates
    f32x4 arz[RZT];
    #pragma unroll
    for (int i=0;i<RZT;++i) arz[i]=zero4;
    wgemm<RZT>(arz, wihrz, KXP, XBUFb, 328, wv, r16, g);
    wgemm<RZT>(arz, whhrz, KHP, HSTb, 200, wv, r16, g);
    #pragma unroll
    for (int i=0;i<RZT;++i){
        int n = (wv+4*i)*16 + r16;
        #pragma unroll
        for (int q=0;q<4;++q){
            int m = g*4+q;
            RZb[m*328+n] = f2bf(sigm(arz[i][q]));
        }
    }
    // n gate
    f32x4 gx[NT], gh[NT];
    #pragma unroll
    for (int i=0;i<NT;++i){ gx[i]=zero4; gh[i]=zero4; }
    wgemm<NT>(gx, wihn, KXP, XBUFb, 328, wv, r16, g);
    wgemm<NT>(gh, whhn, KHP, HSTb, 200, wv, r16, g);
    __syncthreads();
    f32x4 hkeep[NT];
    #pragma unroll
    for (int i=0;i<NT;++i){
        int n = (wv+4*i)*16 + r16;
        #pragma unroll
        for (int q=0;q<4;++q){
            int m = g*4+q;
            float h = 0.f;
            if (n < H){
                float r = bf2f(RZb[m*328+n]);
                float z = bf2f(RZb[m*328+H+n]);
                float hp = sglob[(long)(row0+m)*H + n];
                float nn = tanh_f(gx[i][q] + r*gh[i][q]);
                h = (1.f-z)*nn + z*hp;
                out[outbase + (long)(row0+m)*H + n] = h;
            }
            hkeep[i][q] = h;
            if (n < HP) HBb[m*200+n] = f2bf(h);
        }
    }
    __syncthreads();
    // GLU
    f32x4 gl[NT];
    #pragma unroll
    for (int i=0;i<NT;++i) gl[i]=zero4;
    wgemm<NT>(gl, wglu, KGP, HBb, 200, wv, r16, g);
    #pragma unroll
    for (int i=0;i<NT;++i){
        int n = (wv+4*i)*16 + r16;
        #pragma unroll
        for (int q=0;q<4;++q){
            int m = g*4+q;
            if (n < H){
                float gv = hkeep[i][q]*sigm(gl[i][q]);
                uint16_t b = f2bf(gv);
                SKIPB[m*712 + gslot + n] = b;
                if (toXbuf) XBUFb[m*328 + n] = b;
            }
        }
    }
    __syncthreads();
}

// ---------------- main kernel: 16 rows / block ----------------
extern "C" __global__ __launch_bounds__(256, 2)
void fargan_mfma(const float* __restrict__ cond, const float* __restrict__ prev_pred,
                 const float* __restrict__ exc_mem, const float* __restrict__ period,
                 const float* __restrict__ s1, const float* __restrict__ s2,
                 const float* __restrict__ s3, const float* __restrict__ s4,
                 const float* __restrict__ w_gain, const float* __restrict__ b_gain,
                 const float* __restrict__ w_pg, const float* __restrict__ b_pg,
                 const uint16_t* __restrict__ W, float* __restrict__ out)
{
    __shared__ __align__(16) uint16_t TRANS[16896];
    __shared__ __align__(16) uint16_t SKIPB[11392];   // [16][712]
    __shared__ float GAIN[16];
    __shared__ float PG[16][4];
    __shared__ float FPITCH[16][40];

    const int tid = threadIdx.x;
    const int row0 = blockIdx.x * 16;
    const int wv = tid >> 6, l = tid & 63, r16 = l & 15, g = l >> 4;
    const int rr = tid >> 4, c16 = tid & 15;
    const long grow = row0 + rr;

    uint16_t* XCATb  = TRANS;          // [16][392], KP 384
    uint16_t* FWRAWb = TRANS + 6272;   // [16][200], KP 192
    uint16_t* XBUFb  = TRANS;          // [16][328]
    uint16_t* RZb    = TRANS + 5248;   // [16][328]
    uint16_t* HSTb   = TRANS + 10496;  // [16][200]
    uint16_t* HBb    = TRANS + 13696;  // [16][200]
    uint16_t* SKb    = TRANS;          // [16][136]
    uint16_t* SK2b   = TRANS + 2176;   // [16][136]

    // ======== stage A ========
    const float* exc_row = exc_mem + grow*256;

    float a0 = 0.f;
    for (int i=c16;i<80;i+=16) a0 += cond[grow*80+i]*w_gain[i];
    a0 += __shfl_xor(a0,8,16); a0 += __shfl_xor(a0,4,16);
    a0 += __shfl_xor(a0,2,16); a0 += __shfl_xor(a0,1,16);
    float gn = 0.2f + 0.8f*sigm(a0 + b_gain[0]);
    if (!(gn==gn)) gn = 1.0f;
    gn = fminf(fmaxf(gn, 0.001f), 20.0f);
    float inv = 1.0f/(1e-5f+gn);
    if (c16==0) GAIN[rr] = gn;

    float p = period[grow];
    p = (fabsf(p) <= 3.0e38f) ? p : 128.0f;
    p = fminf(fmaxf(p, 32.0f), 255.0f);

    for (int e=c16;e<44;e+=16){
        float idxf = 254.0f - p + (float)e;
        float idx0 = floorf(idxf);
        float al = fminf(fmaxf(idxf-idx0, 0.f), 1.f);
        int i0 = (int)fminf(fmaxf(idx0, 0.f), 255.f);
        int i1 = (int)fminf(fmaxf(idx0+1.f, 0.f), 255.f);
        float pr = (1.f-al)*exc_row[i0] + al*exc_row[i1];
        float pn = pr*inv;
        XCATb[rr*392+244+e] = f2bf(pn);
        out[ONS4 + grow*164 + 80 + e] = pn;
        if (e>=2 && e<42){
            out[OPREV + grow*256 + 216 + (e-2)] = pr;
            FPITCH[rr][e-2] = pn;
        }
    }
    for (int i=c16;i<40;i+=16){
        float pv = exc_row[216+i]*inv;
        uint16_t b = f2bf(pv);
        XCATb[rr*392+288+i] = b;
        SKIPB[rr*712+648+i] = b;
        out[ONS4 + grow*164 + 124 + i] = pv;
    }
    for (int i=c16;i<80;i+=16){
        float cv = cond[grow*80+i];
        XCATb[rr*392+164+i] = f2bf(cv);
        out[ONS4 + grow*164 + i] = cv;
    }
    for (int i=c16;i<164;i+=16) XCATb[rr*392+i] = f2bf(s4[grow*164+i]);
    for (int i=328+c16;i<384;i+=16) XCATb[rr*392+i] = 0;
    for (int i=c16;i<160;i+=16) HSTb[rr*200+i] = f2bf(s1[grow*160+i]);
    for (int i=160+c16;i<192;i+=16) HSTb[rr*200+i] = 0;
    for (int i=688+c16;i<704;i+=16) SKIPB[rr*712+i] = 0;
    for (int i=c16;i<216;i+=16){
        out[OPREV + grow*256 + i] = prev_pred[grow*256 + 40 + i];
        out[OEXC  + grow*256 + i] = exc_row[40+i];
    }
    __syncthreads();

    f32x4 zero4 = {0.f,0.f,0.f,0.f};

    // ======== fwc0: [16][384] @ [192][384]^T ========
    f32x4 fwk[3], acc3[3];
    #pragma unroll
    for (int i=0;i<3;++i) acc3[i] = zero4;
    wgemm<3>(acc3, W + W_F0, 384, XCATb, 392, wv, r16, g);
    #pragma unroll
    for (int i=0;i<3;++i){
        int n = (wv+4*i)*16 + r16;
        #pragma unroll
        for (int q=0;q<4;++q){
            int m = g*4+q;
            float t = tanh_f(acc3[i][q]);
            fwk[i][q] = t;
            FWRAWb[m*200+n] = f2bf(t);
        }
    }
    __syncthreads();
    #pragma unroll
    for (int i=0;i<3;++i) acc3[i] = zero4;
    wgemm<3>(acc3, W + W_F0G, 192, FWRAWb, 200, wv, r16, g);
    #pragma unroll
    for (int i=0;i<3;++i){
        int n = (wv+4*i)*16 + r16;
        #pragma unroll
        for (int q=0;q<4;++q){
            int m = g*4+q;
            float v = fwk[i][q]*sigm(acc3[i][q]);
            uint16_t b = f2bf(v);
            SKIPB[m*712 + 416 + n] = b;   // FWC0 slot
            XBUFb[m*328 + n] = b;         // GRU1 x[0:192]
        }
    }
    __syncthreads();

    // ======== pitch gain (wave 0): pg[m][n] = sigm(FWC0 . w_pg[n] + b_pg[n]) ========
    if (wv == 0){
        int m = r16, n = g;
        float acc = 0.f;
        for (int k=0;k<192;++k) acc += bf2f(SKIPB[m*712+416+k]) * w_pg[n*192+k];
        PG[m][n] = sigm(acc + b_pg[n]);
    }
    __syncthreads();

    // ======== GRU1 xbuf tail: PF@192, PREV@232, zeros 272..319 ========
    for (int i=c16;i<40;i+=16){
        XBUFb[rr*328+192+i] = f2bf(PG[rr][0]*FPITCH[rr][i]);
        XBUFb[rr*328+232+i] = SKIPB[rr*712+648+i];
    }
    for (int i=272+c16;i<320;i+=16) XBUFb[rr*328+i] = 0;
    __syncthreads();

    // ======== GRU1: H=160 ========
    gru_stage<160,5,3>(W+W_IH1RZ, W+W_HH1RZ, W+W_IH1N, W+W_HH1N, W+W_GLU1,
                       320, 192, 192, 192,
                       XBUFb, RZb, HSTb, HBb, s1, out, OH1,
                       SKIPB, 0, true, row0, wv, r16, g);

    // between: HST=s2; PF@160 (pg1), PREV@200, zeros 240..255
    for (int i=c16;i<128;i+=16) HSTb[rr*200+i] = f2bf(s2[grow*128+i]);
    for (int i=c16;i<40;i+=16){
        XBUFb[rr*328+160+i] = f2bf(PG[rr][1]*FPITCH[rr][i]);
        XBUFb[rr*328+200+i] = SKIPB[rr*712+648+i];
    }
    for (int i=240+c16;i<256;i+=16) XBUFb[rr*328+i] = 0;
    __syncthreads();

    // ======== GRU2: H=128 ========
    gru_stage<128,4,2>(W+W_IH2RZ, W+W_HH2RZ, W+W_IH2N, W+W_HH2N, W+W_GLU2,
                       256, 128, 128, 128,
                       XBUFb, RZb, HSTb, HBb, s2, out, OH2,
                       SKIPB, 160, true, row0, wv, r16, g);

    // between: HST=s3; PF@128 (pg2), PREV@168, zeros 208..255
    for (int i=c16;i<128;i+=16) HSTb[rr*200+i] = f2bf(s3[grow*128+i]);
    for (int i=c16;i<40;i+=16){
        XBUFb[rr*328+128+i] = f2bf(PG[rr][2]*FPITCH[rr][i]);
        XBUFb[rr*328+168+i] = SKIPB[rr*712+648+i];
    }
    for (int i=208+c16;i<256;i+=16) XBUFb[rr*328+i] = 0;
    __syncthreads();

    // ======== GRU3: H=128 ========
    gru_stage<128,4,2>(W+W_IH3RZ, W+W_HH3RZ, W+W_IH3N, W+W_HH3N, W+W_GLU3,
                       256, 128, 128, 128,
                       XBUFb, RZb, HSTb, HBb, s3, out, OH3,
                       SKIPB, 288, false, row0, wv, r16, g);

    // ======== skip PF slot (pg3) ========
    for (int i=c16;i<40;i+=16) SKIPB[rr*712+608+i] = f2bf(PG[rr][3]*FPITCH[rr][i]);
    __syncthreads();

    // ======== skip: [16][704] @ [128][704]^T ========
    f32x4 skk[2], a2[2];
    #pragma unroll
    for (int i=0;i<2;++i) a2[i] = zero4;
    wgemm<2>(a2, W + W_SKIP, 704, SKIPB, 712, wv, r16, g);
    #pragma unroll
    for (int i=0;i<2;++i){
        int n = (wv+4*i)*16 + r16;
        #pragma unroll
        for (int q=0;q<4;++q){
            int m = g*4+q;
            float t = tanh_f(a2[i][q]);
            skk[i][q] = t;
            SKb[m*136+n] = f2bf(t);
        }
    }
    __syncthreads();
    #pragma unroll
    for (int i=0;i<2;++i) a2[i] = zero4;
    wgemm<2>(a2, W + W_SKIPG, 128, SKb, 136, wv, r16, g);
    #pragma unroll
    for (int i=0;i<2;++i){
        int n = (wv+4*i)*16 + r16;
        #pragma unroll
        for (int q=0;q<4;++q){
            int m = g*4+q;
            SK2b[m*136+n] = f2bf(skk[i][q]*sigm(a2[i][q]));
        }
    }
    __syncthreads();

    // ======== sig: [16][128] @ [64][128]^T, write sig_out + exc tail ========
    f32x4 a1[1];
    a1[0] = zero4;
    wgemm<1>(a1, W + W_SIG, 128, SK2b, 136, wv, r16, g);
    {
        int n = wv*16 + r16;
        if (n < 40){
            #pragma unroll
            for (int q=0;q<4;++q){
                int m = g*4+q;
                float s = tanh_f(a1[0][q]) * GAIN[m];
                out[OSIG + (long)(row0+m)*40 + n] = s;
                out[OEXC + (long)(row0+m)*256 + 216 + n] = s;
            }
        }
    }
}

extern "C" void kernel_launch(void* const* d_in, const int* in_sizes, int n_in,
                              void* d_out, int out_size, void* d_ws, size_t ws_size,
                              hipStream_t stream) {
    const float* cond      = (const float*)d_in[0];
    const float* prev_pred = (const float*)d_in[1];
    const float* exc_mem   = (const float*)d_in[2];
    const float* period    = (const float*)d_in[3];
    const float* s1        = (const float*)d_in[4];
    const float* s2        = (const float*)d_in[5];
    const float* s3        = (const float*)d_in[6];
    const float* s4        = (const float*)d_in[7];
    const float* w_gain    = (const float*)d_in[8];
    const float* b_gain    = (const float*)d_in[9];
    const float* w_fwc0    = (const float*)d_in[10];
    const float* w_fwc0_glu= (const float*)d_in[11];
    const float* wih1      = (const float*)d_in[12];
    const float* whh1      = (const float*)d_in[13];
    const float* wglu1     = (const float*)d_in[14];
    const float* wih2      = (const float*)d_in[15];
    const float* whh2      = (const float*)d_in[16];
    const float* wglu2     = (const float*)d_in[17];
    const float* wih3      = (const float*)d_in[18];
    const float* whh3      = (const float*)d_in[19];
    const float* wglu3     = (const float*)d_in[20];
    const float* w_skip    = (const float*)d_in[21];
    const float* w_skip_glu= (const float*)d_in[22];
    const float* w_sig     = (const float*)d_in[23];
    const float* w_pg      = (const float*)d_in[24];
    const float* b_pg      = (const float*)d_in[25];
    float* out = (float*)d_out;
    uint16_t* wsbf = (uint16_t*)d_ws;

    PrepArgs pa;
    pa.s[0]=w_fwc0; pa.s[1]=w_fwc0_glu; pa.s[2]=wih1; pa.s[3]=whh1; pa.s[4]=wglu1;
    pa.s[5]=wih2; pa.s[6]=whh2; pa.s[7]=wglu2; pa.s[8]=wih3; pa.s[9]=whh3;
    pa.s[10]=wglu3; pa.s[11]=w_skip; pa.s[12]=w_skip_glu; pa.s[13]=w_sig;

    hipLaunchKernelGGL(prep_kernel, dim3(3712), dim3(64), 0, stream, pa, wsbf);
    hipLaunchKernelGGL(fargan_mfma, dim3(2048), dim3(256), 0, stream,
        cond, prev_pred, exc_mem, period, s1, s2, s3, s4,
        w_gain, b_gain, w_pg, b_pg, wsbf, out);
}

// Round 4
// 365.407 us; speedup vs baseline: 20.5584x; 1.3795x over previous
//
#include <hip/hip_runtime.h>
#include <cstdint>
#include <cmath>

#define BTOT 32768L
#define OSIG 0L
#define OEXC (BTOT*40L)
#define OPREV (OEXC + BTOT*256L)
#define OH1 (OPREV + BTOT*256L)
#define OH2 (OH1 + BTOT*160L)
#define OH3 (OH2 + BTOT*128L)
#define ONS4 (OH3 + BTOT*128L)

typedef __attribute__((ext_vector_type(8))) short short8;
typedef __attribute__((ext_vector_type(4))) float f32x4;

// ws layout (bf16 elements). All blocks [Npad][KP], row-major, zero-padded.
#define W_F0     0L        // [192][352]
#define W_F0G    67584L    // [192][192]
#define W_PG     104448L   // [16][192]
#define W_IH1R   107520L   // [192][288]
#define W_IH1Z   162816L
#define W_IH1N   218112L
#define W_HH1R   273408L   // [192][192]
#define W_HH1Z   310272L
#define W_HH1N   347136L
#define W_GLU1   384000L   // [192][192]
#define W_IH2R   420864L   // [128][256]
#define W_IH2Z   453632L
#define W_IH2N   486400L
#define W_HH2R   519168L   // [128][128]
#define W_HH2Z   535552L
#define W_HH2N   551936L
#define W_GLU2   568320L   // [128][128]
#define W_IH3R   584704L   // [128][224]
#define W_IH3Z   613376L
#define W_IH3N   642048L
#define W_HH3R   670720L   // [128][128]
#define W_HH3Z   687104L
#define W_HH3N   703488L
#define W_GLU3   719872L   // [128][128]
#define W_SKIP   736256L   // [128][704]
#define W_SKIPG  826368L   // [128][128]
#define W_SIG    842752L   // [64][128]

__device__ __forceinline__ float sigm(float x){ return 1.0f/(1.0f+__expf(-x)); }
__device__ __forceinline__ float tanh_f(float x){
    float e = __expf(2.0f*x);
    return 1.0f - 2.0f/(e+1.0f);
}
__device__ __forceinline__ uint16_t f2bf(float x){
    union { float f; uint32_t u; } v; v.f = x;
    uint32_t r = v.u + 0x7FFFu + ((v.u>>16)&1u);
    return (uint16_t)(r>>16);
}

// ---------------- prep: fp32 weights -> padded bf16 blocks in ws ----------------
struct PrepArgs { const float* s[15]; };

__global__ __launch_bounds__(64) void prep_kernel(PrepArgs pa, uint16_t* dst){
    // srcidx, rowoff, Nvalid, K, KP, Npad, dstoff
    static const int J[27][7] = {
        {0,  0,192,328,352,192, 0},
        {1,  0,192,192,192,192, 67584},
        {13, 0,  4,192,192, 16, 104448},
        {2,  0,160,272,288,192, 107520},
        {2,160,160,272,288,192, 162816},
        {2,320,160,272,288,192, 218112},
        {3,  0,160,160,192,192, 273408},
        {3,160,160,160,192,192, 310272},
        {3,320,160,160,192,192, 347136},
        {4,  0,160,160,192,192, 384000},
        {5,  0,128,240,256,128, 420864},
        {5,128,128,240,256,128, 453632},
        {5,256,128,240,256,128, 486400},
        {6,  0,128,128,128,128, 519168},
        {6,128,128,128,128,128, 535552},
        {6,256,128,128,128,128, 551936},
        {7,  0,128,128,128,128, 568320},
        {8,  0,128,208,224,128, 584704},
        {8,128,128,208,224,128, 613376},
        {8,256,128,208,224,128, 642048},
        {9,  0,128,128,128,128, 670720},
        {9,128,128,128,128,128, 687104},
        {9,256,128,128,128,128, 703488},
        {10, 0,128,128,128,128, 719872},
        {11, 0,128,688,704,128, 736256},
        {12, 0,128,128,128,128, 826368},
        {14, 0, 40,128,128, 64, 842752},
    };
    int row = blockIdx.x;
    int j = 0;
    while (row >= J[j][5]) { row -= J[j][5]; ++j; }
    const float* src = pa.s[J[j][0]];
    const int ro = J[j][1], N = J[j][2], K = J[j][3], KP = J[j][4];
    uint16_t* d = dst + (long)J[j][6] + (long)row*KP;
    for (int k = threadIdx.x; k < KP; k += 64){
        float v = (row < N && k < K) ? src[(long)(ro+row)*K + k] : 0.0f;
        d[k] = f2bf(v);
    }
}

// ---------------- dual-m-tile wave GEMM ----------------
// A: LDS bf16 [32][P]; rows r16 (m-tile0) and 16+r16 (m-tile1)
// B: global bf16 [Npad][KP]; wave w covers n-tiles {w+8i, i<CNT}
// One B fragment feeds two MFMAs. Full compile-time unroll.
template<int KS, int CNT>
__device__ __forceinline__ void wgemm2(f32x4* acc0, f32x4* acc1,
    const uint16_t* __restrict__ Bw, int KP,
    const uint16_t* A, int P, int w, int r16, int g)
{
    const uint16_t* a0 = A + r16*P + g*8;
    const uint16_t* a1 = a0 + 16*P;
    const uint16_t* bp[CNT];
    #pragma unroll
    for (int i=0;i<CNT;++i)
        bp[i] = Bw + (size_t)((w + 8*i)*16 + r16)*KP + g*8;
    #pragma unroll
    for (int s=0;s<KS;++s){
        short8 af0 = *(const short8*)(a0 + s*32);
        short8 af1 = *(const short8*)(a1 + s*32);
        #pragma unroll
        for (int i=0;i<CNT;++i){
            short8 bf = *(const short8*)(bp[i] + s*32);
            acc0[i] = __builtin_amdgcn_mfma_f32_16x16x32_bf16(af0, bf, acc0[i],0,0,0);
            acc1[i] = __builtin_amdgcn_mfma_f32_16x16x32_bf16(af1, bf, acc1[i],0,0,0);
        }
    }
}

// ---------------- GRU h-phase (no barriers inside) ----------------
template<int KSX, int KSH, int CNT>
__device__ __forceinline__ void gru_h(
    const uint16_t* Wrx, const uint16_t* Wzx, const uint16_t* Wnx, int KXP,
    const uint16_t* Wrh, const uint16_t* Wzh, const uint16_t* Wnh, int KHP,
    const uint16_t* XB, const uint16_t* HS,
    const float* __restrict__ sg, int H, float* __restrict__ outp, long obase,
    uint16_t* HBp, int HWIN,
    float hk0[][4], float hk1[][4],
    int row0, int w, int r16, int g)
{
    // prefetch h_prev early (consumed after 6 GEMMs)
    float hp0[CNT][4], hp1[CNT][4];
    #pragma unroll
    for (int i=0;i<CNT;++i){
        int n = (w+8*i)*16 + r16;
        #pragma unroll
        for (int q=0;q<4;++q){
            int m0 = g*4+q;
            hp0[i][q] = (n<H) ? sg[(long)(row0+m0)*H + n] : 0.f;
            hp1[i][q] = (n<H) ? sg[(long)(row0+16+m0)*H + n] : 0.f;
        }
    }
    f32x4 z4 = {0.f,0.f,0.f,0.f};
    f32x4 gx0[CNT],gx1[CNT],gh0[CNT],gh1[CNT],ra0[CNT],ra1[CNT],za0[CNT],za1[CNT];
    #pragma unroll
    for (int i=0;i<CNT;++i){ gx0[i]=z4; gx1[i]=z4; gh0[i]=z4; gh1[i]=z4; ra0[i]=z4; ra1[i]=z4; za0[i]=z4; za1[i]=z4; }
    wgemm2<KSX,CNT>(gx0,gx1, Wnx, KXP, XB, 392, w,r16,g);
    wgemm2<KSH,CNT>(gh0,gh1, Wnh, KHP, HS, 200, w,r16,g);
    wgemm2<KSX,CNT>(ra0,ra1, Wrx, KXP, XB, 392, w,r16,g);
    wgemm2<KSH,CNT>(ra0,ra1, Wrh, KHP, HS, 200, w,r16,g);
    wgemm2<KSX,CNT>(za0,za1, Wzx, KXP, XB, 392, w,r16,g);
    wgemm2<KSH,CNT>(za0,za1, Wzh, KHP, HS, 200, w,r16,g);
    #pragma unroll
    for (int i=0;i<CNT;++i){
        int n = (w+8*i)*16 + r16;
        #pragma unroll
        for (int q=0;q<4;++q){
            int m0 = g*4+q, m1 = 16+m0;
            float h0 = 0.f, h1 = 0.f;
            if (n < H){
                float r0 = sigm(ra0[i][q]), zz0 = sigm(za0[i][q]);
                float nn0 = tanh_f(gx0[i][q] + r0*gh0[i][q]);
                h0 = (1.f-zz0)*nn0 + zz0*hp0[i][q];
                outp[obase + (long)(row0+m0)*H + n] = h0;
                float r1 = sigm(ra1[i][q]), zz1 = sigm(za1[i][q]);
                float nn1 = tanh_f(gx1[i][q] + r1*gh1[i][q]);
                h1 = (1.f-zz1)*nn1 + zz1*hp1[i][q];
                outp[obase + (long)(row0+m1)*H + n] = h1;
            }
            hk0[i][q]=h0; hk1[i][q]=h1;
            if (n < HWIN){ HBp[m0*200+n]=f2bf(h0); HBp[m1*200+n]=f2bf(h1); }
        }
    }
}

template<int KSG, int CNT>
__device__ __forceinline__ void gru_glu(
    const uint16_t* Wg, int KGP, const uint16_t* HBp,
    float hk0[][4], float hk1[][4], int H,
    uint16_t* SKIPp, int gslot, uint16_t* XBp, bool toX,
    int w, int r16, int g)
{
    f32x4 z4 = {0.f,0.f,0.f,0.f};
    f32x4 gl0[CNT], gl1[CNT];
    #pragma unroll
    for (int i=0;i<CNT;++i){ gl0[i]=z4; gl1[i]=z4; }
    wgemm2<KSG,CNT>(gl0,gl1, Wg, KGP, HBp, 200, w,r16,g);
    #pragma unroll
    for (int i=0;i<CNT;++i){
        int n = (w+8*i)*16 + r16;
        if (n < H){
            #pragma unroll
            for (int q=0;q<4;++q){
                int m0 = g*4+q, m1 = 16+m0;
                uint16_t b0 = f2bf(hk0[i][q]*sigm(gl0[i][q]));
                uint16_t b1 = f2bf(hk1[i][q]*sigm(gl1[i][q]));
                SKIPp[m0*712+gslot+n] = b0; SKIPp[m1*712+gslot+n] = b1;
                if (toX){ XBp[m0*392+n] = b0; XBp[m1*392+n] = b1; }
            }
        }
    }
}

// ---------------- main kernel: 32 rows / block, 512 threads ----------------
extern "C" __global__ __launch_bounds__(512, 2)
void fargan_mfma(const float* __restrict__ cond, const float* __restrict__ prev_pred,
                 const float* __restrict__ exc_mem, const float* __restrict__ period,
                 const float* __restrict__ s1, const float* __restrict__ s2,
                 const float* __restrict__ s3, const float* __restrict__ s4,
                 const float* __restrict__ w_gain, const float* __restrict__ b_gain,
                 const float* __restrict__ b_pg,
                 const uint16_t* __restrict__ W, float* __restrict__ out)
{
    __shared__ __align__(16) uint16_t XBUF[32*392];   // XCAT / XBUF / SK,SK2 overlay
    __shared__ __align__(16) uint16_t FWRAW[32*200];
    __shared__ __align__(16) uint16_t HST[32*200];
    __shared__ __align__(16) uint16_t HB[32*200];
    __shared__ __align__(16) uint16_t SKIPB[32*712];
    __shared__ float GAIN[32];
    __shared__ float PGs[32][4];
    __shared__ float FPITCH[32][40];

    const int tid = threadIdx.x;
    const int row0 = blockIdx.x * 32;
    const int w = tid >> 6, l = tid & 63, r16 = l & 15, g = l >> 4;
    const int rr = tid >> 4, c16 = tid & 15;
    const long grow = row0 + rr;

    uint16_t* SKb  = XBUF;            // [32][136]
    uint16_t* SK2b = XBUF + 32*136;   // [32][136]

    // ======== stage A ========
    const float* exc_row = exc_mem + grow*256;

    float a0 = 0.f;
    for (int i=c16;i<80;i+=16) a0 += cond[grow*80+i]*w_gain[i];
    a0 += __shfl_xor(a0,8,16); a0 += __shfl_xor(a0,4,16);
    a0 += __shfl_xor(a0,2,16); a0 += __shfl_xor(a0,1,16);
    float gn = 0.2f + 0.8f*sigm(a0 + b_gain[0]);
    if (!(gn==gn)) gn = 1.0f;
    gn = fminf(fmaxf(gn, 0.001f), 20.0f);
    float inv = 1.0f/(1e-5f+gn);
    if (c16==0) GAIN[rr] = gn;

    float p = period[grow];
    p = (fabsf(p) <= 3.0e38f) ? p : 128.0f;
    p = fminf(fmaxf(p, 32.0f), 255.0f);

    for (int e=c16;e<44;e+=16){
        float idxf = 254.0f - p + (float)e;
        float idx0 = floorf(idxf);
        float al = fminf(fmaxf(idxf-idx0, 0.f), 1.f);
        int i0 = (int)fminf(fmaxf(idx0, 0.f), 255.f);
        int i1 = (int)fminf(fmaxf(idx0+1.f, 0.f), 255.f);
        float pr = (1.f-al)*exc_row[i0] + al*exc_row[i1];
        float pn = pr*inv;
        XBUF[rr*392+244+e] = f2bf(pn);           // XCAT pred_n
        out[ONS4 + grow*164 + 80 + e] = pn;
        if (e>=2 && e<42){
            out[OPREV + grow*256 + 216 + (e-2)] = pr;
            FPITCH[rr][e-2] = pn;
        }
    }
    for (int i=c16;i<40;i+=16){
        float pv = exc_row[216+i]*inv;
        uint16_t b = f2bf(pv);
        XBUF[rr*392+288+i] = b;                  // XCAT prev
        SKIPB[rr*712+648+i] = b;                 // skip prev slot
        out[ONS4 + grow*164 + 124 + i] = pv;
    }
    for (int i=c16;i<80;i+=16){
        float cv = cond[grow*80+i];
        XBUF[rr*392+164+i] = f2bf(cv);           // XCAT cond
        out[ONS4 + grow*164 + i] = cv;
    }
    for (int i=c16;i<164;i+=16) XBUF[rr*392+i] = f2bf(s4[grow*164+i]);  // XCAT s4
    for (int i=328+c16;i<352;i+=16) XBUF[rr*392+i] = 0;
    for (int i=c16;i<160;i+=16) HST[rr*200+i] = f2bf(s1[grow*160+i]);
    for (int i=160+c16;i<192;i+=16) HST[rr*200+i] = 0;
    for (int i=688+c16;i<704;i+=16) SKIPB[rr*712+i] = 0;
    for (int i=c16;i<216;i+=16){
        out[OPREV + grow*256 + i] = prev_pred[grow*256 + 40 + i];
        out[OEXC  + grow*256 + i] = exc_row[40+i];
    }
    __syncthreads();

    f32x4 z4 = {0.f,0.f,0.f,0.f};
    float fwk0[2][4], fwk1[2][4];

    // ======== fwc0: tanh(XCAT @ W_F0^T), Npad=192 (T=12) ========
    {
        f32x4 a0v[2], a1v[2];
        if (w < 4){
            a0v[0]=z4; a0v[1]=z4; a1v[0]=z4; a1v[1]=z4;
            wgemm2<11,2>(a0v,a1v, W+W_F0, 352, XBUF, 392, w,r16,g);
            #pragma unroll
            for (int i=0;i<2;++i){
                int n = (w+8*i)*16 + r16;
                #pragma unroll
                for (int q=0;q<4;++q){
                    int m0=g*4+q, m1=16+m0;
                    float t0 = tanh_f(a0v[i][q]), t1 = tanh_f(a1v[i][q]);
                    fwk0[i][q]=t0; fwk1[i][q]=t1;
                    FWRAW[m0*200+n]=f2bf(t0); FWRAW[m1*200+n]=f2bf(t1);
                }
            }
        } else {
            a0v[0]=z4; a1v[0]=z4;
            wgemm2<11,1>(a0v,a1v, W+W_F0, 352, XBUF, 392, w,r16,g);
            int n = w*16 + r16;
            #pragma unroll
            for (int q=0;q<4;++q){
                int m0=g*4+q, m1=16+m0;
                float t0 = tanh_f(a0v[0][q]), t1 = tanh_f(a1v[0][q]);
                fwk0[0][q]=t0; fwk1[0][q]=t1;
                FWRAW[m0*200+n]=f2bf(t0); FWRAW[m1*200+n]=f2bf(t1);
            }
        }
    }
    __syncthreads();

    // ======== f0g GLU: fw * sigm(FWRAW @ W_F0G^T) -> SKIPB[416+], XBUF[0:192) ========
    {
        f32x4 a0v[2], a1v[2];
        if (w < 4){
            a0v[0]=z4; a0v[1]=z4; a1v[0]=z4; a1v[1]=z4;
            wgemm2<6,2>(a0v,a1v, W+W_F0G, 192, FWRAW, 200, w,r16,g);
            #pragma unroll
            for (int i=0;i<2;++i){
                int n = (w+8*i)*16 + r16;
                #pragma unroll
                for (int q=0;q<4;++q){
                    int m0=g*4+q, m1=16+m0;
                    uint16_t b0 = f2bf(fwk0[i][q]*sigm(a0v[i][q]));
                    uint16_t b1 = f2bf(fwk1[i][q]*sigm(a1v[i][q]));
                    SKIPB[m0*712+416+n]=b0; SKIPB[m1*712+416+n]=b1;
                    XBUF[m0*392+n]=b0; XBUF[m1*392+n]=b1;
                }
            }
        } else {
            a0v[0]=z4; a1v[0]=z4;
            wgemm2<6,1>(a0v,a1v, W+W_F0G, 192, FWRAW, 200, w,r16,g);
            int n = w*16 + r16;
            #pragma unroll
            for (int q=0;q<4;++q){
                int m0=g*4+q, m1=16+m0;
                uint16_t b0 = f2bf(fwk0[0][q]*sigm(a0v[0][q]));
                uint16_t b1 = f2bf(fwk1[0][q]*sigm(a1v[0][q]));
                SKIPB[m0*712+416+n]=b0; SKIPB[m1*712+416+n]=b1;
                XBUF[m0*392+n]=b0; XBUF[m1*392+n]=b1;
            }
        }
    }
    __syncthreads();

    // ======== pitch gain via MFMA (all waves redundant, wave 0 writes) ========
    {
        f32x4 pa0[1], pa1[1];
        pa0[0]=z4; pa1[0]=z4;
        wgemm2<6,1>(pa0,pa1, W+W_PG, 192, XBUF, 392, 0, r16, g);
        if (w==0 && r16<4){
            float bp = b_pg[r16];
            #pragma unroll
            for (int q=0;q<4;++q){
                PGs[g*4+q][r16]    = sigm(pa0[0][q] + bp);
                PGs[16+g*4+q][r16] = sigm(pa1[0][q] + bp);
            }
        }
    }
    __syncthreads();
    // PF1 + prev + zero tail for GRU1 x-window [0,288)
    for (int i=c16;i<40;i+=16){
        XBUF[rr*392+192+i] = f2bf(PGs[rr][0]*FPITCH[rr][i]);
        XBUF[rr*392+232+i] = SKIPB[rr*712+648+i];
    }
    for (int i=272+c16;i<288;i+=16) XBUF[rr*392+i] = 0;
    __syncthreads();

    // ======== GRU1: H=160, HP=192 (T=12) ========
    float hk0[2][4], hk1[2][4];
    if (w < 4)
        gru_h<9,6,2>(W+W_IH1R,W+W_IH1Z,W+W_IH1N,288, W+W_HH1R,W+W_HH1Z,W+W_HH1N,192,
                     XBUF,HST, s1,160,out,OH1, HB,192, hk0,hk1, row0,w,r16,g);
    else
        gru_h<9,6,1>(W+W_IH1R,W+W_IH1Z,W+W_IH1N,288, W+W_HH1R,W+W_HH1Z,W+W_HH1N,192,
                     XBUF,HST, s1,160,out,OH1, HB,192, hk0,hk1, row0,w,r16,g);
    __syncthreads();
    if (w < 4)
        gru_glu<6,2>(W+W_GLU1,192, HB, hk0,hk1,160, SKIPB,0, XBUF,true, w,r16,g);
    else
        gru_glu<6,1>(W+W_GLU1,192, HB, hk0,hk1,160, SKIPB,0, XBUF,true, w,r16,g);
    __syncthreads();

    // between 1->2: HST<-s2; x-window [g1(160)|pf(40)|prev(40)|0) = 256
    for (int i=c16;i<128;i+=16) HST[rr*200+i] = f2bf(s2[grow*128+i]);
    for (int i=c16;i<40;i+=16){
        XBUF[rr*392+160+i] = f2bf(PGs[rr][1]*FPITCH[rr][i]);
        XBUF[rr*392+200+i] = SKIPB[rr*712+648+i];
    }
    for (int i=240+c16;i<256;i+=16) XBUF[rr*392+i] = 0;
    __syncthreads();

    // ======== GRU2: H=128, HP=128 (T=8) ========
    gru_h<8,4,1>(W+W_IH2R,W+W_IH2Z,W+W_IH2N,256, W+W_HH2R,W+W_HH2Z,W+W_HH2N,128,
                 XBUF,HST, s2,128,out,OH2, HB,128, hk0,hk1, row0,w,r16,g);
    __syncthreads();
    gru_glu<4,1>(W+W_GLU2,128, HB, hk0,hk1,128, SKIPB,160, XBUF,true, w,r16,g);
    __syncthreads();

    // between 2->3: HST<-s3; x-window [g2(128)|pf(40)|prev(40)|0) = 224
    for (int i=c16;i<128;i+=16) HST[rr*200+i] = f2bf(s3[grow*128+i]);
    for (int i=c16;i<40;i+=16){
        XBUF[rr*392+128+i] = f2bf(PGs[rr][2]*FPITCH[rr][i]);
        XBUF[rr*392+168+i] = SKIPB[rr*712+648+i];
    }
    for (int i=208+c16;i<224;i+=16) XBUF[rr*392+i] = 0;
    __syncthreads();

    // ======== GRU3: H=128 ========
    gru_h<7,4,1>(W+W_IH3R,W+W_IH3Z,W+W_IH3N,224, W+W_HH3R,W+W_HH3Z,W+W_HH3N,128,
                 XBUF,HST, s3,128,out,OH3, HB,128, hk0,hk1, row0,w,r16,g);
    __syncthreads();
    gru_glu<4,1>(W+W_GLU3,128, HB, hk0,hk1,128, SKIPB,288, (uint16_t*)nullptr,false, w,r16,g);
    __syncthreads();

    // skip pf slot
    for (int i=c16;i<40;i+=16) SKIPB[rr*712+608+i] = f2bf(PGs[rr][3]*FPITCH[rr][i]);
    __syncthreads();

    // ======== skip: tanh(SKIPB @ W_SKIP^T), T=8 ========
    float skk0[4], skk1[4];
    {
        f32x4 a0v[1], a1v[1];
        a0v[0]=z4; a1v[0]=z4;
        wgemm2<22,1>(a0v,a1v, W+W_SKIP, 704, SKIPB, 712, w,r16,g);
        int n = w*16 + r16;
        #pragma unroll
        for (int q=0;q<4;++q){
            int m0=g*4+q, m1=16+m0;
            float t0 = tanh_f(a0v[0][q]), t1 = tanh_f(a1v[0][q]);
            skk0[q]=t0; skk1[q]=t1;
            SKb[m0*136+n]=f2bf(t0); SKb[m1*136+n]=f2bf(t1);
        }
    }
    __syncthreads();
    // ======== skip GLU ========
    {
        f32x4 a0v[1], a1v[1];
        a0v[0]=z4; a1v[0]=z4;
        wgemm2<4,1>(a0v,a1v, W+W_SKIPG, 128, SKb, 136, w,r16,g);
        int n = w*16 + r16;
        #pragma unroll
        for (int q=0;q<4;++q){
            int m0=g*4+q, m1=16+m0;
            SK2b[m0*136+n]=f2bf(skk0[q]*sigm(a0v[0][q]));
            SK2b[m1*136+n]=f2bf(skk1[q]*sigm(a1v[0][q]));
        }
    }
    __syncthreads();
    // ======== sig: waves 0-3, Npad=64, valid n<40 ========
    if (w < 4){
        f32x4 a0v[1], a1v[1];
        a0v[0]=z4; a1v[0]=z4;
        wgemm2<4,1>(a0v,a1v, W+W_SIG, 128, SK2b, 136, w,r16,g);
        int n = w*16 + r16;
        if (n < 40){
            #pragma unroll
            for (int q=0;q<4;++q){
                int m0=g*4+q, m1=16+m0;
                float s0 = tanh_f(a0v[0][q]) * GAIN[m0];
                float s1v = tanh_f(a1v[0][q]) * GAIN[m1];
                out[OSIG + (long)(row0+m0)*40 + n] = s0;
                out[OEXC + (long)(row0+m0)*256 + 216 + n] = s0;
                out[OSIG + (long)(row0+m1)*40 + n] = s1v;
                out[OEXC + (long)(row0+m1)*256 + 216 + n] = s1v;
            }
        }
    }
}

extern "C" void kernel_launch(void* const* d_in, const int* in_sizes, int n_in,
                              void* d_out, int out_size, void* d_ws, size_t ws_size,
                              hipStream_t stream) {
    const float* cond      = (const float*)d_in[0];
    const float* prev_pred = (const float*)d_in[1];
    const float* exc_mem   = (const float*)d_in[2];
    const float* period    = (const float*)d_in[3];
    const float* s1        = (const float*)d_in[4];
    const float* s2        = (const float*)d_in[5];
    const float* s3        = (const float*)d_in[6];
    const float* s4        = (const float*)d_in[7];
    const float* w_gain    = (const float*)d_in[8];
    const float* b_gain    = (const float*)d_in[9];
    const float* w_fwc0    = (const float*)d_in[10];
    const float* w_fwc0_glu= (const float*)d_in[11];
    const float* wih1      = (const float*)d_in[12];
    const float* whh1      = (const float*)d_in[13];
    const float* wglu1     = (const float*)d_in[14];
    const float* wih2      = (const float*)d_in[15];
    const float* whh2      = (const float*)d_in[16];
    const float* wglu2     = (const float*)d_in[17];
    const float* wih3      = (const float*)d_in[18];
    const float* whh3      = (const float*)d_in[19];
    const float* wglu3     = (const float*)d_in[20];
    const float* w_skip    = (const float*)d_in[21];
    const float* w_skip_glu= (const float*)d_in[22];
    const float* w_sig     = (const float*)d_in[23];
    const float* w_pg      = (const float*)d_in[24];
    const float* b_pg      = (const float*)d_in[25];
    float* out = (float*)d_out;
    uint16_t* wsbf = (uint16_t*)d_ws;

    PrepArgs pa;
    pa.s[0]=w_fwc0; pa.s[1]=w_fwc0_glu; pa.s[2]=wih1; pa.s[3]=whh1; pa.s[4]=wglu1;
    pa.s[5]=wih2; pa.s[6]=whh2; pa.s[7]=wglu2; pa.s[8]=wih3; pa.s[9]=whh3;
    pa.s[10]=wglu3; pa.s[11]=w_skip; pa.s[12]=w_skip_glu; pa.s[13]=w_pg; pa.s[14]=w_sig;

    hipLaunchKernelGGL(prep_kernel, dim3(3856), dim3(64), 0, stream, pa, wsbf);
    hipLaunchKernelGGL(fargan_mfma, dim3(1024), dim3(512), 0, stream,
        cond, prev_pred, exc_mem, period, s1, s2, s3, s4,
        w_gain, b_gain, b_pg, wsbf, out);
}

// Round 5
// 345.171 us; speedup vs baseline: 21.7636x; 1.0586x over previous
//
#include <hip/hip_runtime.h>
#include <cstdint>
#include <cmath>

#define BTOT 32768L
#define OSIG 0L
#define OEXC (BTOT*40L)
#define OPREV (OEXC + BTOT*256L)
#define OH1 (OPREV + BTOT*256L)
#define OH2 (OH1 + BTOT*160L)
#define OH3 (OH2 + BTOT*128L)
#define ONS4 (OH3 + BTOT*128L)

typedef __attribute__((ext_vector_type(8))) short short8;
typedef __attribute__((ext_vector_type(4))) float f32x4;

#define AP 968   // ACT pitch (elems); 968*2/4 % 32 == 4

// ACT column map (per row):
//  [0,192)   fwc0            (skip: fwc0 part)      | stage A: XCAT s4@0,cond@164,pred_n@244,prev@288,z@328..352
//  [192,232) pf1   [232,272) prev (skip prev part)  [272,288) zeros
//  [288,448) g1    [448,488) pf2  [488,528) prev    [528,544) zeros
//  [544,672) g2    [672,712) pf3  [712,752) prev    [752,768) zeros
//  [544,736)  = HST1 window during GRU1 (s1+zeros)
//  [352,544)  = FWRAW during fwc0 phases
//  [768,896) g3    [896,936) pf4  [936,960) zeros
//  [768,960)  = HB1 window during GRU1 (h+zeros)

// ws layout (bf16 elements). All blocks [Npad][KP], row-major, zero-padded.
#define W_F0     0L        // [192][352]
#define W_F0G    67584L    // [192][192]
#define W_PG     104448L   // [16][192]
#define W_IH1R   107520L   // [192][288]
#define W_IH1Z   162816L
#define W_IH1N   218112L
#define W_HH1R   273408L   // [192][192]
#define W_HH1Z   310272L
#define W_HH1N   347136L
#define W_GLU1   384000L   // [192][192]
#define W_IH2R   420864L   // [128][256]
#define W_IH2Z   453632L
#define W_IH2N   486400L
#define W_HH2R   519168L   // [128][128]
#define W_HH2Z   535552L
#define W_HH2N   551936L
#define W_GLU2   568320L   // [128][128]
#define W_IH3R   584704L   // [128][224]
#define W_IH3Z   613376L
#define W_IH3N   642048L
#define W_HH3R   670720L   // [128][128]
#define W_HH3Z   687104L
#define W_HH3N   703488L
#define W_GLU3   719872L   // [128][128]
#define W_SKIP   736256L   // [128][960] column-permuted to ACT map
#define W_SKIPG  859136L   // [128][128]
#define W_SIG    875520L   // [64][128]

__device__ __forceinline__ float sigm(float x){ return 1.0f/(1.0f+__expf(-x)); }
__device__ __forceinline__ float tanh_f(float x){
    float e = __expf(2.0f*x);
    return 1.0f - 2.0f/(e+1.0f);
}
__device__ __forceinline__ uint16_t f2bf(float x){
    union { float f; uint32_t u; } v; v.f = x;
    uint32_t r = v.u + 0x7FFFu + ((v.u>>16)&1u);
    return (uint16_t)(r>>16);
}
__device__ __forceinline__ float bf2f(uint16_t h){
    union { float f; uint32_t u; } v; v.u = ((uint32_t)h)<<16;
    return v.f;
}

// ---------------- prep: fp32 weights -> padded bf16 blocks in ws ----------------
struct PrepArgs { const float* s[15]; };

__global__ __launch_bounds__(64) void prep_kernel(PrepArgs pa, uint16_t* dst){
    // srcidx, rowoff, Nvalid, Ksrc, KP, Npad, dstoff, type (0=straight, 1=skip remap)
    static const long J[27][8] = {
        {0,  0,192,328,352,192, W_F0,   0},
        {1,  0,192,192,192,192, W_F0G,  0},
        {13, 0,  4,192,192, 16, W_PG,   0},
        {2,  0,160,272,288,192, W_IH1R, 0},
        {2,160,160,272,288,192, W_IH1Z, 0},
        {2,320,160,272,288,192, W_IH1N, 0},
        {3,  0,160,160,192,192, W_HH1R, 0},
        {3,160,160,160,192,192, W_HH1Z, 0},
        {3,320,160,160,192,192, W_HH1N, 0},
        {4,  0,160,160,192,192, W_GLU1, 0},
        {5,  0,128,240,256,128, W_IH2R, 0},
        {5,128,128,240,256,128, W_IH2Z, 0},
        {5,256,128,240,256,128, W_IH2N, 0},
        {6,  0,128,128,128,128, W_HH2R, 0},
        {6,128,128,128,128,128, W_HH2Z, 0},
        {6,256,128,128,128,128, W_HH2N, 0},
        {7,  0,128,128,128,128, W_GLU2, 0},
        {8,  0,128,208,224,128, W_IH3R, 0},
        {8,128,128,208,224,128, W_IH3Z, 0},
        {8,256,128,208,224,128, W_IH3N, 0},
        {9,  0,128,128,128,128, W_HH3R, 0},
        {9,128,128,128,128,128, W_HH3Z, 0},
        {9,256,128,128,128,128, W_HH3N, 0},
        {10, 0,128,128,128,128, W_GLU3, 0},
        {11, 0,128,688,960,128, W_SKIP, 1},
        {12, 0,128,128,128,128, W_SKIPG,0},
        {14, 0, 40,128,128, 64, W_SIG,  0},
    };
    long row = blockIdx.x;
    int j = 0;
    while (row >= J[j][5]) { row -= J[j][5]; ++j; }
    const float* src = pa.s[J[j][0]];
    const long ro = J[j][1], N = J[j][2], K = J[j][3], KP = J[j][4];
    const int type = (int)J[j][7];
    uint16_t* d = dst + J[j][6] + row*KP;
    for (long k = threadIdx.x; k < KP; k += 64){
        float v = 0.0f;
        if (row < N){
            if (type == 0){
                if (k < K) v = src[(ro+row)*K + k];
            } else {
                // skip remap: dest ACT col k -> src w_skip col
                long s = -1;
                if (k < 192) s = 416 + k;                      // fwc0
                else if (k >= 232 && k < 272) s = 648 + (k-232); // prev
                else if (k >= 288 && k < 448) s = (k-288);       // g1
                else if (k >= 544 && k < 672) s = 160 + (k-544); // g2
                else if (k >= 768 && k < 896) s = 288 + (k-768); // g3
                else if (k >= 896 && k < 936) s = 608 + (k-896); // pf
                if (s >= 0) v = src[row*688 + s];
            }
        }
        d[k] = f2bf(v);
    }
}

// ---------------- dual-m-tile wave GEMM ----------------
template<int KS, int CNT>
__device__ __forceinline__ void wgemm2(f32x4* acc0, f32x4* acc1,
    const uint16_t* __restrict__ Bw, int KP,
    const uint16_t* A, int P, int w, int r16, int g)
{
    const uint16_t* a0 = A + r16*P + g*8;
    const uint16_t* a1 = a0 + 16*P;
    const uint16_t* bp[CNT];
    #pragma unroll
    for (int i=0;i<CNT;++i)
        bp[i] = Bw + (size_t)((w + 8*i)*16 + r16)*KP + g*8;
    #pragma unroll
    for (int s=0;s<KS;++s){
        short8 af0 = *(const short8*)(a0 + s*32);
        short8 af1 = *(const short8*)(a1 + s*32);
        #pragma unroll
        for (int i=0;i<CNT;++i){
            short8 bf = *(const short8*)(bp[i] + s*32);
            acc0[i] = __builtin_amdgcn_mfma_f32_16x16x32_bf16(af0, bf, acc0[i],0,0,0);
            acc1[i] = __builtin_amdgcn_mfma_f32_16x16x32_bf16(af1, bf, acc1[i],0,0,0);
        }
    }
}

// ---------------- GRU h-phase: 6 GEMMs + combine; h kept in regs ----------------
template<int KSX, int KSH, int CNT>
__device__ __forceinline__ void gru_h(
    const uint16_t* Wrx, const uint16_t* Wzx, const uint16_t* Wnx, int KXP,
    const uint16_t* Wrh, const uint16_t* Wzh, const uint16_t* Wnh, int KHP,
    const uint16_t* XA, int XP, const uint16_t* HA, int HP,
    const float* __restrict__ sg, int H, float* __restrict__ outp, long obase,
    float hk0[][4], float hk1[][4],
    int row0, int w, int r16, int g)
{
    float hp0[CNT][4], hp1[CNT][4];
    #pragma unroll
    for (int i=0;i<CNT;++i){
        int n = (w+8*i)*16 + r16;
        #pragma unroll
        for (int q=0;q<4;++q){
            int m0 = g*4+q;
            hp0[i][q] = (n<H) ? sg[(long)(row0+m0)*H + n] : 0.f;
            hp1[i][q] = (n<H) ? sg[(long)(row0+16+m0)*H + n] : 0.f;
        }
    }
    f32x4 z4 = {0.f,0.f,0.f,0.f};
    f32x4 gx0[CNT],gx1[CNT],gh0[CNT],gh1[CNT],ra0[CNT],ra1[CNT],za0[CNT],za1[CNT];
    #pragma unroll
    for (int i=0;i<CNT;++i){ gx0[i]=z4; gx1[i]=z4; gh0[i]=z4; gh1[i]=z4; ra0[i]=z4; ra1[i]=z4; za0[i]=z4; za1[i]=z4; }
    wgemm2<KSX,CNT>(gx0,gx1, Wnx, KXP, XA, XP, w,r16,g);
    wgemm2<KSH,CNT>(gh0,gh1, Wnh, KHP, HA, HP, w,r16,g);
    wgemm2<KSX,CNT>(ra0,ra1, Wrx, KXP, XA, XP, w,r16,g);
    wgemm2<KSH,CNT>(ra0,ra1, Wrh, KHP, HA, HP, w,r16,g);
    wgemm2<KSX,CNT>(za0,za1, Wzx, KXP, XA, XP, w,r16,g);
    wgemm2<KSH,CNT>(za0,za1, Wzh, KHP, HA, HP, w,r16,g);
    #pragma unroll
    for (int i=0;i<CNT;++i){
        int n = (w+8*i)*16 + r16;
        #pragma unroll
        for (int q=0;q<4;++q){
            int m0 = g*4+q, m1 = 16+m0;
            float h0 = 0.f, h1 = 0.f;
            if (n < H){
                float r0 = sigm(ra0[i][q]), zz0 = sigm(za0[i][q]);
                float nn0 = tanh_f(gx0[i][q] + r0*gh0[i][q]);
                h0 = (1.f-zz0)*nn0 + zz0*hp0[i][q];
                outp[obase + (long)(row0+m0)*H + n] = h0;
                float r1 = sigm(ra1[i][q]), zz1 = sigm(za1[i][q]);
                float nn1 = tanh_f(gx1[i][q] + r1*gh1[i][q]);
                h1 = (1.f-zz1)*nn1 + zz1*hp1[i][q];
                outp[obase + (long)(row0+m1)*H + n] = h1;
            }
            hk0[i][q]=h0; hk1[i][q]=h1;
        }
    }
}

// ---------------- main kernel: 32 rows / block, 512 threads, 2 blocks/CU ----------------
extern "C" __global__ __launch_bounds__(512, 4)
void fargan_mfma(const float* __restrict__ cond, const float* __restrict__ prev_pred,
                 const float* __restrict__ exc_mem, const float* __restrict__ period,
                 const float* __restrict__ s1, const float* __restrict__ s2,
                 const float* __restrict__ s3, const float* __restrict__ s4,
                 const float* __restrict__ w_gain, const float* __restrict__ b_gain,
                 const float* __restrict__ b_pg,
                 const uint16_t* __restrict__ W, float* __restrict__ out)
{
    __shared__ __align__(16) uint16_t ACT[32*AP];
    __shared__ __align__(16) uint16_t SH[32*136];
    __shared__ uint16_t FPITCHb[32*40];
    __shared__ float GAIN[32];
    __shared__ float PGs[32][4];

    const int tid = threadIdx.x;
    const int row0 = blockIdx.x * 32;
    const int w = tid >> 6, l = tid & 63, r16 = l & 15, g = l >> 4;
    const int rr = tid >> 4, c16 = tid & 15;
    const long grow = row0 + rr;

    // ======== stage A ========
    const float* exc_row = exc_mem + grow*256;

    float a0 = 0.f;
    for (int i=c16;i<80;i+=16) a0 += cond[grow*80+i]*w_gain[i];
    a0 += __shfl_xor(a0,8,16); a0 += __shfl_xor(a0,4,16);
    a0 += __shfl_xor(a0,2,16); a0 += __shfl_xor(a0,1,16);
    float gn = 0.2f + 0.8f*sigm(a0 + b_gain[0]);
    if (!(gn==gn)) gn = 1.0f;
    gn = fminf(fmaxf(gn, 0.001f), 20.0f);
    float inv = 1.0f/(1e-5f+gn);
    if (c16==0) GAIN[rr] = gn;

    float p = period[grow];
    p = (fabsf(p) <= 3.0e38f) ? p : 128.0f;
    p = fminf(fmaxf(p, 32.0f), 255.0f);

    for (int e=c16;e<44;e+=16){
        float idxf = 254.0f - p + (float)e;
        float idx0 = floorf(idxf);
        float al = fminf(fmaxf(idxf-idx0, 0.f), 1.f);
        int i0 = (int)fminf(fmaxf(idx0, 0.f), 255.f);
        int i1 = (int)fminf(fmaxf(idx0+1.f, 0.f), 255.f);
        float pr = (1.f-al)*exc_row[i0] + al*exc_row[i1];
        float pn = pr*inv;
        ACT[rr*AP + 244 + e] = f2bf(pn);             // XCAT pred_n
        out[ONS4 + grow*164 + 80 + e] = pn;
        if (e>=2 && e<42){
            out[OPREV + grow*256 + 216 + (e-2)] = pr;
            FPITCHb[rr*40 + (e-2)] = f2bf(pn);
        }
    }
    for (int i=c16;i<40;i+=16){
        float pv = exc_row[216+i]*inv;
        ACT[rr*AP + 288 + i] = f2bf(pv);             // XCAT prev (also copied to 232 later)
        out[ONS4 + grow*164 + 124 + i] = pv;
    }
    for (int i=c16;i<80;i+=16){
        float cv = cond[grow*80+i];
        ACT[rr*AP + 164 + i] = f2bf(cv);             // XCAT cond
        out[ONS4 + grow*164 + i] = cv;
    }
    for (int i=c16;i<164;i+=16) ACT[rr*AP + i] = f2bf(s4[grow*164+i]);   // XCAT s4
    for (int i=328+c16;i<352;i+=16) ACT[rr*AP + i] = 0;                  // XCAT zero tail
    for (int i=c16;i<160;i+=16) ACT[rr*AP + 544 + i] = f2bf(s1[grow*160+i]); // HST1
    for (int i=704+c16;i<736;i+=16) ACT[rr*AP + i] = 0;                  // HST1 zero tail
    for (int i=c16;i<216;i+=16){
        out[OPREV + grow*256 + i] = prev_pred[grow*256 + 40 + i];
        out[OEXC  + grow*256 + i] = exc_row[40+i];
    }
    __syncthreads();

    f32x4 z4 = {0.f,0.f,0.f,0.f};
    float fwk0[2][4], fwk1[2][4];

    // ======== fwc0: tanh(XCAT @ W_F0^T) -> FWRAW @ ACT[352,544) ========
    if (w < 4){
        f32x4 a0v[2]={z4,z4}, a1v[2]={z4,z4};
        wgemm2<11,2>(a0v,a1v, W+W_F0, 352, ACT, AP, w,r16,g);
        #pragma unroll
        for (int i=0;i<2;++i){
            int n = (w+8*i)*16 + r16;
            #pragma unroll
            for (int q=0;q<4;++q){
                int m0=g*4+q, m1=16+m0;
                float t0 = tanh_f(a0v[i][q]), t1 = tanh_f(a1v[i][q]);
                fwk0[i][q]=t0; fwk1[i][q]=t1;
                ACT[m0*AP+352+n]=f2bf(t0); ACT[m1*AP+352+n]=f2bf(t1);
            }
        }
    } else {
        f32x4 a0v[1]={z4}, a1v[1]={z4};
        wgemm2<11,1>(a0v,a1v, W+W_F0, 352, ACT, AP, w,r16,g);
        int n = w*16 + r16;
        #pragma unroll
        for (int q=0;q<4;++q){
            int m0=g*4+q, m1=16+m0;
            float t0 = tanh_f(a0v[0][q]), t1 = tanh_f(a1v[0][q]);
            fwk0[0][q]=t0; fwk1[0][q]=t1;
            ACT[m0*AP+352+n]=f2bf(t0); ACT[m1*AP+352+n]=f2bf(t1);
        }
    }
    __syncthreads();

    // ======== f0g GLU: fw*sigm(FWRAW @ W_F0G^T) -> fwc0 @ ACT[0,192) ========
    if (w < 4){
        f32x4 a0v[2]={z4,z4}, a1v[2]={z4,z4};
        wgemm2<6,2>(a0v,a1v, W+W_F0G, 192, ACT+352, AP, w,r16,g);
        #pragma unroll
        for (int i=0;i<2;++i){
            int n = (w+8*i)*16 + r16;
            #pragma unroll
            for (int q=0;q<4;++q){
                int m0=g*4+q, m1=16+m0;
                ACT[m0*AP+n]=f2bf(fwk0[i][q]*sigm(a0v[i][q]));
                ACT[m1*AP+n]=f2bf(fwk1[i][q]*sigm(a1v[i][q]));
            }
        }
    } else {
        f32x4 a0v[1]={z4}, a1v[1]={z4};
        wgemm2<6,1>(a0v,a1v, W+W_F0G, 192, ACT+352, AP, w,r16,g);
        int n = w*16 + r16;
        #pragma unroll
        for (int q=0;q<4;++q){
            int m0=g*4+q, m1=16+m0;
            ACT[m0*AP+n]=f2bf(fwk0[0][q]*sigm(a0v[0][q]));
            ACT[m1*AP+n]=f2bf(fwk1[0][q]*sigm(a1v[0][q]));
        }
    }
    __syncthreads();

    // ======== pitch gain via MFMA (all waves redundant, wave 0 writes) ========
    {
        f32x4 pa0[1]={z4}, pa1[1]={z4};
        wgemm2<6,1>(pa0,pa1, W+W_PG, 192, ACT, AP, 0, r16, g);
        if (w==0 && r16<4){
            float bp = b_pg[r16];
            #pragma unroll
            for (int q=0;q<4;++q){
                PGs[g*4+q][r16]    = sigm(pa0[0][q] + bp);
                PGs[16+g*4+q][r16] = sigm(pa1[0][q] + bp);
            }
        }
    }
    __syncthreads();

    // ======== pf1 @192, prev @232 (copy from XCAT prev @288), zeros [272,288) ========
    for (int i=c16;i<40;i+=16){
        ACT[rr*AP+192+i] = f2bf(PGs[rr][0]*bf2f(FPITCHb[rr*40+i]));
        ACT[rr*AP+232+i] = ACT[rr*AP+288+i];
    }
    for (int i=272+c16;i<288;i+=16) ACT[rr*AP+i] = 0;
    __syncthreads();

    // ======== GRU1: x=[0,288) K=288, h=[544,736) K=192, H=160 ========
    float hk0[2][4], hk1[2][4];
    if (w < 4){
        gru_h<9,6,2>(W+W_IH1R,W+W_IH1Z,W+W_IH1N,288, W+W_HH1R,W+W_HH1Z,W+W_HH1N,192,
                     ACT, AP, ACT+544, AP, s1, 160, out, OH1, hk0, hk1, row0,w,r16,g);
        #pragma unroll
        for (int i=0;i<2;++i){
            int n = (w+8*i)*16 + r16;
            #pragma unroll
            for (int q=0;q<4;++q){
                int m0=g*4+q, m1=16+m0;
                ACT[m0*AP+768+n]=f2bf(hk0[i][q]); ACT[m1*AP+768+n]=f2bf(hk1[i][q]);  // HB1 (h or 0)
            }
        }
    } else {
        gru_h<9,6,1>(W+W_IH1R,W+W_IH1Z,W+W_IH1N,288, W+W_HH1R,W+W_HH1Z,W+W_HH1N,192,
                     ACT, AP, ACT+544, AP, s1, 160, out, OH1, hk0, hk1, row0,w,r16,g);
        int n = w*16 + r16;
        #pragma unroll
        for (int q=0;q<4;++q){
            int m0=g*4+q, m1=16+m0;
            ACT[m0*AP+768+n]=f2bf(hk0[0][q]); ACT[m1*AP+768+n]=f2bf(hk1[0][q]);
        }
    }
    __syncthreads();

    // ======== GLU1: g1 = h*sigm(HB1 @ W_GLU1^T) -> ACT[288,448); + stage s2/pf2/prev ========
    if (w < 4){
        f32x4 gl0[2]={z4,z4}, gl1[2]={z4,z4};
        wgemm2<6,2>(gl0,gl1, W+W_GLU1, 192, ACT+768, AP, w,r16,g);
        #pragma unroll
        for (int i=0;i<2;++i){
            int n = (w+8*i)*16 + r16;
            if (n < 160){
                #pragma unroll
                for (int q=0;q<4;++q){
                    int m0=g*4+q, m1=16+m0;
                    ACT[m0*AP+288+n]=f2bf(hk0[i][q]*sigm(gl0[i][q]));
                    ACT[m1*AP+288+n]=f2bf(hk1[i][q]*sigm(gl1[i][q]));
                }
            }
        }
    } else {
        f32x4 gl0[1]={z4}, gl1[1]={z4};
        wgemm2<6,1>(gl0,gl1, W+W_GLU1, 192, ACT+768, AP, w,r16,g);
        int n = w*16 + r16;
        #pragma unroll
        for (int q=0;q<4;++q){
            int m0=g*4+q, m1=16+m0;
            ACT[m0*AP+288+n]=f2bf(hk0[0][q]*sigm(gl0[0][q]));
            ACT[m1*AP+288+n]=f2bf(hk1[0][q]*sigm(gl1[0][q]));
        }
    }
    // staged writes for GRU2 (regions untouched this phase)
    for (int i=c16;i<128;i+=16) SH[rr*136+i] = f2bf(s2[grow*128+i]);
    for (int i=c16;i<40;i+=16){
        ACT[rr*AP+448+i] = f2bf(PGs[rr][1]*bf2f(FPITCHb[rr*40+i]));
        ACT[rr*AP+488+i] = ACT[rr*AP+232+i];
    }
    for (int i=528+c16;i<544;i+=16) ACT[rr*AP+i] = 0;
    __syncthreads();

    // ======== GRU2: x=[288,544) K=256, h=SH K=128, H=128 ========
    gru_h<8,4,1>(W+W_IH2R,W+W_IH2Z,W+W_IH2N,256, W+W_HH2R,W+W_HH2Z,W+W_HH2N,128,
                 ACT+288, AP, SH, 136, s2, 128, out, OH2, hk0, hk1, row0,w,r16,g);
    __syncthreads();
    {   // HB2 overwrites SH (h-state dead)
        int n = w*16 + r16;
        #pragma unroll
        for (int q=0;q<4;++q){
            int m0=g*4+q, m1=16+m0;
            SH[m0*136+n]=f2bf(hk0[0][q]); SH[m1*136+n]=f2bf(hk1[0][q]);
        }
    }
    __syncthreads();
    // GLU2 -> g2 @ ACT[544,672); + pf3/prev/zeros
    {
        f32x4 gl0[1]={z4}, gl1[1]={z4};
        wgemm2<4,1>(gl0,gl1, W+W_GLU2, 128, SH, 136, w,r16,g);
        int n = w*16 + r16;
        #pragma unroll
        for (int q=0;q<4;++q){
            int m0=g*4+q, m1=16+m0;
            ACT[m0*AP+544+n]=f2bf(hk0[0][q]*sigm(gl0[0][q]));
            ACT[m1*AP+544+n]=f2bf(hk1[0][q]*sigm(gl1[0][q]));
        }
    }
    for (int i=c16;i<40;i+=16){
        ACT[rr*AP+672+i] = f2bf(PGs[rr][2]*bf2f(FPITCHb[rr*40+i]));
        ACT[rr*AP+712+i] = ACT[rr*AP+232+i];
    }
    for (int i=752+c16;i<768;i+=16) ACT[rr*AP+i] = 0;
    __syncthreads();

    // SH <- s3
    for (int i=c16;i<128;i+=16) SH[rr*136+i] = f2bf(s3[grow*128+i]);
    __syncthreads();

    // ======== GRU3: x=[544,768) K=224, h=SH K=128, H=128 ========
    gru_h<7,4,1>(W+W_IH3R,W+W_IH3Z,W+W_IH3N,224, W+W_HH3R,W+W_HH3Z,W+W_HH3N,128,
                 ACT+544, AP, SH, 136, s3, 128, out, OH3, hk0, hk1, row0,w,r16,g);
    __syncthreads();
    {   // HB3 overwrites SH
        int n = w*16 + r16;
        #pragma unroll
        for (int q=0;q<4;++q){
            int m0=g*4+q, m1=16+m0;
            SH[m0*136+n]=f2bf(hk0[0][q]); SH[m1*136+n]=f2bf(hk1[0][q]);
        }
    }
    __syncthreads();
    // GLU3 -> g3 @ ACT[768,896); + pf4 @ [896,936)
    {
        f32x4 gl0[1]={z4}, gl1[1]={z4};
        wgemm2<4,1>(gl0,gl1, W+W_GLU3, 128, SH, 136, w,r16,g);
        int n = w*16 + r16;
        #pragma unroll
        for (int q=0;q<4;++q){
            int m0=g*4+q, m1=16+m0;
            ACT[m0*AP+768+n]=f2bf(hk0[0][q]*sigm(gl0[0][q]));
            ACT[m1*AP+768+n]=f2bf(hk1[0][q]*sigm(gl1[0][q]));
        }
    }
    for (int i=c16;i<40;i+=16)
        ACT[rr*AP+896+i] = f2bf(PGs[rr][3]*bf2f(FPITCHb[rr*40+i]));
    __syncthreads();

    // ======== skip: tanh(ACT[0,960) @ W_SKIP^T) ========
    float skk0[4], skk1[4];
    {
        f32x4 a0v[1]={z4}, a1v[1]={z4};
        wgemm2<30,1>(a0v,a1v, W+W_SKIP, 960, ACT, AP, w,r16,g);
        int n = w*16 + r16;
        #pragma unroll
        for (int q=0;q<4;++q){
            int m0=g*4+q, m1=16+m0;
            skk0[q]=tanh_f(a0v[0][q]); skk1[q]=tanh_f(a1v[0][q]);
            SH[m0*136+n]=f2bf(skk0[q]); SH[m1*136+n]=f2bf(skk1[q]);   // SK (SH dead)
        }
    }
    __syncthreads();
    // ======== skip GLU -> SK2 @ ACT[0,128) ========
    {
        f32x4 a0v[1]={z4}, a1v[1]={z4};
        wgemm2<4,1>(a0v,a1v, W+W_SKIPG, 128, SH, 136, w,r16,g);
        int n = w*16 + r16;
        #pragma unroll
        for (int q=0;q<4;++q){
            int m0=g*4+q, m1=16+m0;
            ACT[m0*AP+n]=f2bf(skk0[q]*sigm(a0v[0][q]));
            ACT[m1*AP+n]=f2bf(skk1[q]*sigm(a1v[0][q]));
        }
    }
    __syncthreads();
    // ======== sig: waves 0-3, Npad=64, valid n<40 ========
    if (w < 4){
        f32x4 a0v[1]={z4}, a1v[1]={z4};
        wgemm2<4,1>(a0v,a1v, W+W_SIG, 128, ACT, AP, w,r16,g);
        int n = w*16 + r16;
        if (n < 40){
            #pragma unroll
            for (int q=0;q<4;++q){
                int m0=g*4+q, m1=16+m0;
                float sv0 = tanh_f(a0v[0][q]) * GAIN[m0];
                float sv1 = tanh_f(a1v[0][q]) * GAIN[m1];
                out[OSIG + (long)(row0+m0)*40 + n] = sv0;
                out[OEXC + (long)(row0+m0)*256 + 216 + n] = sv0;
                out[OSIG + (long)(row0+m1)*40 + n] = sv1;
                out[OEXC + (long)(row0+m1)*256 + 216 + n] = sv1;
            }
        }
    }
}

extern "C" void kernel_launch(void* const* d_in, const int* in_sizes, int n_in,
                              void* d_out, int out_size, void* d_ws, size_t ws_size,
                              hipStream_t stream) {
    const float* cond      = (const float*)d_in[0];
    const float* prev_pred = (const float*)d_in[1];
    const float* exc_mem   = (const float*)d_in[2];
    const float* period    = (const float*)d_in[3];
    const float* s1        = (const float*)d_in[4];
    const float* s2        = (const float*)d_in[5];
    const float* s3        = (const float*)d_in[6];
    const float* s4        = (const float*)d_in[7];
    const float* w_gain    = (const float*)d_in[8];
    const float* b_gain    = (const float*)d_in[9];
    const float* w_fwc0    = (const float*)d_in[10];
    const float* w_fwc0_glu= (const float*)d_in[11];
    const float* wih1      = (const float*)d_in[12];
    const float* whh1      = (const float*)d_in[13];
    const float* wglu1     = (const float*)d_in[14];
    const float* wih2      = (const float*)d_in[15];
    const float* whh2      = (const float*)d_in[16];
    const float* wglu2     = (const float*)d_in[17];
    const float* wih3      = (const float*)d_in[18];
    const float* whh3      = (const float*)d_in[19];
    const float* wglu3     = (const float*)d_in[20];
    const float* w_skip    = (const float*)d_in[21];
    const float* w_skip_glu= (const float*)d_in[22];
    const float* w_sig     = (const float*)d_in[23];
    const float* w_pg      = (const float*)d_in[24];
    const float* b_pg      = (const float*)d_in[25];
    float* out = (float*)d_out;
    uint16_t* wsbf = (uint16_t*)d_ws;

    PrepArgs pa;
    pa.s[0]=w_fwc0; pa.s[1]=w_fwc0_glu; pa.s[2]=wih1; pa.s[3]=whh1; pa.s[4]=wglu1;
    pa.s[5]=wih2; pa.s[6]=whh2; pa.s[7]=wglu2; pa.s[8]=wih3; pa.s[9]=whh3;
    pa.s[10]=wglu3; pa.s[11]=w_skip; pa.s[12]=w_skip_glu; pa.s[13]=w_pg; pa.s[14]=w_sig;

    hipLaunchKernelGGL(prep_kernel, dim3(3856), dim3(64), 0, stream, pa, wsbf);
    hipLaunchKernelGGL(fargan_mfma, dim3(1024), dim3(512), 0, stream,
        cond, prev_pred, exc_mem, period, s1, s2, s3, s4,
        w_gain, b_gain, b_pg, wsbf, out);
}

// Round 8
// 292.291 us; speedup vs baseline: 25.7010x; 1.1809x over previous
//
#include <hip/hip_runtime.h>
#include <cstdint>
#include <cmath>

#define BTOT 32768L
#define OSIG 0L
#define OEXC (BTOT*40L)
#define OPREV (OEXC + BTOT*256L)
#define OH1 (OPREV + BTOT*256L)
#define OH2 (OH1 + BTOT*160L)
#define OH3 (OH2 + BTOT*128L)
#define ONS4 (OH3 + BTOT*128L)

typedef __attribute__((ext_vector_type(8))) short short8;
typedef __attribute__((ext_vector_type(4))) float f32x4;

#define AP 968   // ACT pitch (bf16 elems)

// ACT column map (per row), lifetime-multiplexed:
//  [0,192)   XCAT s4[0,164)/cond[164,244) -> fwc0 (after f0g) -> SK2 (after skip)
//  [192,232) pf1 (written after pg)
//  [232,272) prev stable slot (copied from [288,328) in pf1 phase, AFTER XCAT dead)
//  [244,288) XCAT pred_n (dead after fwc0 GEMM)
//  [288,328) XCAT prev source; then g1 [288,448) (GLU1+)
//  [328,352) zeros (XCAT pad)
//  [352,544) FWRAW -> r-gate(GRU1) -> g1-tail/pf2/prev2
//  [448,488) pf2, [488,528) prev2, [528,544) zeros (GLU1 staging)
//  [544,736) s1-state -> s2-state [544,672) -> g2 [544,672)
//  [672,712) pf3, [712,752) prev3, [752,768) zeros
//  [768,960) z-gate -> HB1 -> HB2 [768,896) -> g3 [768,896), pf4 [896,936), zeros [936,960)

// ws layout (bf16 elements). All blocks [Npad][KP], row-major, zero-padded.
#define W_F0     0L        // [192][352]
#define W_F0G    67584L    // [192][192]
#define W_PG     104448L   // [16][192]
#define W_IH1R   107520L   // [192][288]
#define W_IH1Z   162816L
#define W_IH1N   218112L
#define W_HH1R   273408L   // [192][192]
#define W_HH1Z   310272L
#define W_HH1N   347136L
#define W_GLU1   384000L   // [192][192]
#define W_IH2R   420864L   // [128][256]
#define W_IH2Z   453632L
#define W_IH2N   486400L
#define W_HH2R   519168L   // [128][128]
#define W_HH2Z   535552L
#define W_HH2N   551936L
#define W_GLU2   568320L   // [128][128]
#define W_IH3R   584704L   // [128][224]
#define W_IH3Z   613376L
#define W_IH3N   642048L
#define W_HH3R   670720L   // [128][128]
#define W_HH3Z   687104L
#define W_HH3N   703488L
#define W_GLU3   719872L   // [128][128]
#define W_SKIP   736256L   // [128][960] column-permuted to ACT map
#define W_SKIPG  859136L   // [128][128]
#define W_SIG    875520L   // [64][128]

__device__ __forceinline__ float sigm(float x){ return 1.0f/(1.0f+__expf(-x)); }
__device__ __forceinline__ float tanh_f(float x){
    float e = __expf(2.0f*x);
    return 1.0f - 2.0f/(e+1.0f);
}
__device__ __forceinline__ uint16_t f2bf(float x){
    union { float f; uint32_t u; } v; v.f = x;
    uint32_t r = v.u + 0x7FFFu + ((v.u>>16)&1u);
    return (uint16_t)(r>>16);
}
__device__ __forceinline__ float bf2f(uint16_t h){
    union { float f; uint32_t u; } v; v.u = ((uint32_t)h)<<16;
    return v.f;
}

// ---------------- prep: fp32 weights -> padded bf16 blocks in ws ----------------
struct PrepArgs { const float* s[15]; };

__global__ __launch_bounds__(64) void prep_kernel(PrepArgs pa, uint16_t* dst){
    // srcidx, rowoff, Nvalid, Ksrc, KP, Npad, dstoff, type (0=straight, 1=skip remap)
    static const long J[27][8] = {
        {0,  0,192,328,352,192, W_F0,   0},
        {1,  0,192,192,192,192, W_F0G,  0},
        {13, 0,  4,192,192, 16, W_PG,   0},
        {2,  0,160,272,288,192, W_IH1R, 0},
        {2,160,160,272,288,192, W_IH1Z, 0},
        {2,320,160,272,288,192, W_IH1N, 0},
        {3,  0,160,160,192,192, W_HH1R, 0},
        {3,160,160,160,192,192, W_HH1Z, 0},
        {3,320,160,160,192,192, W_HH1N, 0},
        {4,  0,160,160,192,192, W_GLU1, 0},
        {5,  0,128,240,256,128, W_IH2R, 0},
        {5,128,128,240,256,128, W_IH2Z, 0},
        {5,256,128,240,256,128, W_IH2N, 0},
        {6,  0,128,128,128,128, W_HH2R, 0},
        {6,128,128,128,128,128, W_HH2Z, 0},
        {6,256,128,128,128,128, W_HH2N, 0},
        {7,  0,128,128,128,128, W_GLU2, 0},
        {8,  0,128,208,224,128, W_IH3R, 0},
        {8,128,128,208,224,128, W_IH3Z, 0},
        {8,256,128,208,224,128, W_IH3N, 0},
        {9,  0,128,128,128,128, W_HH3R, 0},
        {9,128,128,128,128,128, W_HH3Z, 0},
        {9,256,128,128,128,128, W_HH3N, 0},
        {10, 0,128,128,128,128, W_GLU3, 0},
        {11, 0,128,688,960,128, W_SKIP, 1},
        {12, 0,128,128,128,128, W_SKIPG,0},
        {14, 0, 40,128,128, 64, W_SIG,  0},
    };
    long row = blockIdx.x;
    int j = 0;
    while (row >= J[j][5]) { row -= J[j][5]; ++j; }
    const float* src = pa.s[J[j][0]];
    const long ro = J[j][1], N = J[j][2], K = J[j][3], KP = J[j][4];
    const int type = (int)J[j][7];
    uint16_t* d = dst + J[j][6] + row*KP;
    for (long k = threadIdx.x; k < KP; k += 64){
        float v = 0.0f;
        if (row < N){
            if (type == 0){
                if (k < K) v = src[(ro+row)*K + k];
            } else {
                long s = -1;
                if (k < 192) s = 416 + k;                        // fwc0
                else if (k >= 232 && k < 272) s = 648 + (k-232); // prev
                else if (k >= 288 && k < 448) s = (k-288);       // g1
                else if (k >= 544 && k < 672) s = 160 + (k-544); // g2
                else if (k >= 768 && k < 896) s = 288 + (k-768); // g3
                else if (k >= 896 && k < 936) s = 608 + (k-896); // pf4
                if (s >= 0) v = src[row*688 + s];
            }
        }
        d[k] = f2bf(v);
    }
}

// ---------------- quad-m-tile wave GEMM: 64 rows, CNT n-tiles ----------------
template<int KS, int CNT>
__device__ __forceinline__ void wgemm4(f32x4 (&acc)[CNT][4],
    const uint16_t* __restrict__ Bw, int KP,
    const uint16_t* A, int P, int w, int r16, int g)
{
    const uint16_t* ap = A + r16*P + g*8;
    const uint16_t* bp[CNT];
    #pragma unroll
    for (int i=0;i<CNT;++i)
        bp[i] = Bw + (size_t)((w + 8*i)*16 + r16)*KP + g*8;
    #pragma unroll
    for (int s=0;s<KS;++s){
        short8 af[4];
        #pragma unroll
        for (int mt=0;mt<4;++mt) af[mt] = *(const short8*)(ap + mt*16*P + s*32);
        #pragma unroll
        for (int i=0;i<CNT;++i){
            short8 bf = *(const short8*)(bp[i] + s*32);
            #pragma unroll
            for (int mt=0;mt<4;++mt)
                acc[i][mt] = __builtin_amdgcn_mfma_f32_16x16x32_bf16(af[mt], bf, acc[i][mt],0,0,0);
        }
    }
}
template<int CNT> __device__ __forceinline__ void zacc(f32x4 (&a)[CNT][4]){
    f32x4 z4 = {0.f,0.f,0.f,0.f};
    #pragma unroll
    for (int i=0;i<CNT;++i){
        #pragma unroll
        for (int mt=0;mt<4;++mt) a[i][mt]=z4;
    }
}

// ---------------- GRU1 phases (H=160, x=[0,288) K288, h=[544,736) K192) ----------------
template<int CNT>
__device__ __forceinline__ void gru1_rz(const uint16_t* __restrict__ W, uint16_t* ACTp,
                                        int w, int r16, int g){
    f32x4 ra[CNT][4], za[CNT][4];
    zacc(ra); zacc(za);
    wgemm4<9,CNT>(ra, W+W_IH1R, 288, ACTp,     AP, w,r16,g);
    wgemm4<6,CNT>(ra, W+W_HH1R, 192, ACTp+544, AP, w,r16,g);
    wgemm4<9,CNT>(za, W+W_IH1Z, 288, ACTp,     AP, w,r16,g);
    wgemm4<6,CNT>(za, W+W_HH1Z, 192, ACTp+544, AP, w,r16,g);
    #pragma unroll
    for (int i=0;i<CNT;++i){
        int n = (w+8*i)*16 + r16;
        #pragma unroll
        for (int mt=0;mt<4;++mt){
            #pragma unroll
            for (int q=0;q<4;++q){
                int mrow = mt*16 + g*4 + q;
                ACTp[mrow*AP + 352 + n] = f2bf(sigm(ra[i][mt][q]));  // r-gate
                ACTp[mrow*AP + 768 + n] = f2bf(sigm(za[i][mt][q]));  // z-gate
            }
        }
    }
}
template<int CNT>
__device__ __forceinline__ void gru1_n(const uint16_t* __restrict__ W, uint16_t* ACTp,
                                       const float* __restrict__ s1, float* __restrict__ out,
                                       float (&hk)[2][4][4], int row0, int w, int r16, int g){
    float hp[CNT][4][4];
    #pragma unroll
    for (int i=0;i<CNT;++i){
        int n = (w+8*i)*16 + r16;
        #pragma unroll
        for (int mt=0;mt<4;++mt)
            #pragma unroll
            for (int q=0;q<4;++q)
                hp[i][mt][q] = (n<160) ? s1[(long)(row0+mt*16+g*4+q)*160 + n] : 0.f;
    }
    f32x4 gx[CNT][4], gh[CNT][4];
    zacc(gx); zacc(gh);
    wgemm4<9,CNT>(gx, W+W_IH1N, 288, ACTp,     AP, w,r16,g);
    wgemm4<6,CNT>(gh, W+W_HH1N, 192, ACTp+544, AP, w,r16,g);
    #pragma unroll
    for (int i=0;i<CNT;++i){
        int n = (w+8*i)*16 + r16;
        #pragma unroll
        for (int mt=0;mt<4;++mt){
            #pragma unroll
            for (int q=0;q<4;++q){
                int mrow = mt*16 + g*4 + q;
                float h = 0.f;
                if (n < 160){
                    float r = bf2f(ACTp[mrow*AP + 352 + n]);
                    float z = bf2f(ACTp[mrow*AP + 768 + n]);
                    float nn = tanh_f(gx[i][mt][q] + r*gh[i][mt][q]);
                    h = (1.f-z)*nn + z*hp[i][mt][q];
                    out[OH1 + (long)(row0+mrow)*160 + n] = h;
                }
                hk[i][mt][q] = h;
                ACTp[mrow*AP + 768 + n] = f2bf(h);   // HB1 (h, zeros for n>=160)
            }
        }
    }
}
template<int CNT>
__device__ __forceinline__ void glu1(const uint16_t* __restrict__ W, uint16_t* ACTp,
                                     float (&hk)[2][4][4], int w, int r16, int g){
    f32x4 gl[CNT][4];
    zacc(gl);
    wgemm4<6,CNT>(gl, W+W_GLU1, 192, ACTp+768, AP, w,r16,g);
    #pragma unroll
    for (int i=0;i<CNT;++i){
        int n = (w+8*i)*16 + r16;
        if (n < 160){
            #pragma unroll
            for (int mt=0;mt<4;++mt)
                #pragma unroll
                for (int q=0;q<4;++q){
                    int mrow = mt*16 + g*4 + q;
                    ACTp[mrow*AP + 288 + n] = f2bf(hk[i][mt][q]*sigm(gl[i][mt][q]));  // g1
                }
        }
    }
}

// ---------------- GRU2 h-phase (H=128, x/h both in ACT with pitch AP) ----------------
template<int KSX>
__device__ __forceinline__ void gru23_h(
    const uint16_t* __restrict__ Wxr, const uint16_t* __restrict__ Wxz, const uint16_t* __restrict__ Wxn, int KPX,
    const uint16_t* __restrict__ Whr, const uint16_t* __restrict__ Whz, const uint16_t* __restrict__ Whn,
    const uint16_t* XA, const uint16_t* HA,
    const float* __restrict__ sg, float* __restrict__ outp, long obase,
    uint16_t* HBdst, float (&hk)[4][4], int row0, int w, int r16, int g)
{
    const int n = w*16 + r16;
    float hp[4][4];
    #pragma unroll
    for (int mt=0;mt<4;++mt)
        #pragma unroll
        for (int q=0;q<4;++q)
            hp[mt][q] = sg[(long)(row0+mt*16+g*4+q)*128 + n];
    f32x4 gx[1][4], gh[1][4], ra[1][4], za[1][4];
    zacc(gx); zacc(gh); zacc(ra); zacc(za);
    wgemm4<KSX,1>(gx, Wxn, KPX, XA, AP, w,r16,g);
    wgemm4<4,1>(gh, Whn, 128, HA, AP, w,r16,g);
    wgemm4<KSX,1>(ra, Wxr, KPX, XA, AP, w,r16,g);
    wgemm4<4,1>(ra, Whr, 128, HA, AP, w,r16,g);
    wgemm4<KSX,1>(za, Wxz, KPX, XA, AP, w,r16,g);
    wgemm4<4,1>(za, Whz, 128, HA, AP, w,r16,g);
    #pragma unroll
    for (int mt=0;mt<4;++mt){
        #pragma unroll
        for (int q=0;q<4;++q){
            int mrow = mt*16 + g*4 + q;
            float r = sigm(ra[0][mt][q]), z = sigm(za[0][mt][q]);
            float nn = tanh_f(gx[0][mt][q] + r*gh[0][mt][q]);
            float h = (1.f-z)*nn + z*hp[mt][q];
            outp[obase + (long)(row0+mrow)*128 + n] = h;
            hk[mt][q] = h;
            HBdst[mrow*AP + n] = f2bf(h);
        }
    }
}

// ---------------- main kernel: 64 rows / block, 512 threads, 1 block/CU ----------------
extern "C" __global__ __launch_bounds__(512, 2)
void fargan_mfma(const float* __restrict__ cond, const float* __restrict__ prev_pred,
                 const float* __restrict__ exc_mem, const float* __restrict__ period,
                 const float* __restrict__ s1, const float* __restrict__ s2,
                 const float* __restrict__ s3, const float* __restrict__ s4,
                 const float* __restrict__ w_gain, const float* __restrict__ b_gain,
                 const float* __restrict__ b_pg,
                 const uint16_t* __restrict__ W, float* __restrict__ out)
{
    __shared__ __align__(16) uint16_t ACT[64*AP];
    __shared__ __align__(16) uint16_t SH[64*136];
    __shared__ uint16_t FPITCHb[64*40];
    __shared__ float GAIN[64];
    __shared__ float PGs[64][4];

    const int tid = threadIdx.x;
    const int row0 = blockIdx.x * 64;
    const int w = tid >> 6, l = tid & 63, r16 = l & 15, g = l >> 4;
    const int rr = tid >> 3, c8 = tid & 7;
    const long grow = row0 + rr;

    // ======== stage A ========
    const float* exc_row = exc_mem + grow*256;

    float a0 = 0.f;
    for (int i=c8;i<80;i+=8) a0 += cond[grow*80+i]*w_gain[i];
    a0 += __shfl_xor(a0,4,8); a0 += __shfl_xor(a0,2,8); a0 += __shfl_xor(a0,1,8);
    float gn = 0.2f + 0.8f*sigm(a0 + b_gain[0]);
    if (!(gn==gn)) gn = 1.0f;
    gn = fminf(fmaxf(gn, 0.001f), 20.0f);
    float inv = 1.0f/(1e-5f+gn);
    if (c8==0) GAIN[rr] = gn;

    float p = period[grow];
    p = (fabsf(p) <= 3.0e38f) ? p : 128.0f;
    p = fminf(fmaxf(p, 32.0f), 255.0f);

    for (int e=c8;e<44;e+=8){
        float idxf = 254.0f - p + (float)e;
        float idx0 = floorf(idxf);
        float al = fminf(fmaxf(idxf-idx0, 0.f), 1.f);
        int i0 = (int)fminf(fmaxf(idx0, 0.f), 255.f);
        int i1 = (int)fminf(fmaxf(idx0+1.f, 0.f), 255.f);
        float pr = (1.f-al)*exc_row[i0] + al*exc_row[i1];
        float pn = pr*inv;
        ACT[rr*AP + 244 + e] = f2bf(pn);             // XCAT pred_n
        out[ONS4 + grow*164 + 80 + e] = pn;
        if (e>=2 && e<42){
            out[OPREV + grow*256 + 216 + (e-2)] = pr;
            FPITCHb[rr*40 + (e-2)] = f2bf(pn);
        }
    }
    for (int i=c8;i<40;i+=8){
        float pv = exc_row[216+i]*inv;
        ACT[rr*AP + 288 + i] = f2bf(pv);             // XCAT prev (stable until GLU1)
        out[ONS4 + grow*164 + 124 + i] = pv;
    }
    for (int i=c8;i<80;i+=8){
        float cv = cond[grow*80+i];
        ACT[rr*AP + 164 + i] = f2bf(cv);             // XCAT cond
        out[ONS4 + grow*164 + i] = cv;
    }
    for (int i=c8;i<164;i+=8) ACT[rr*AP + i] = f2bf(s4[grow*164+i]);        // XCAT s4
    for (int i=328+c8;i<352;i+=8) ACT[rr*AP + i] = 0;                        // XCAT pad
    for (int i=c8;i<160;i+=8) ACT[rr*AP + 544 + i] = f2bf(s1[grow*160+i]);   // s1-state
    for (int i=704+c8;i<736;i+=8) ACT[rr*AP + i] = 0;                        // s1 pad
    for (int i=c8;i<216;i+=8){
        out[OPREV + grow*256 + i] = prev_pred[grow*256 + 40 + i];
        out[OEXC  + grow*256 + i] = exc_row[40+i];
    }
    __syncthreads();

    float fwk[2][4][4];

    // ======== fwc0: tanh(XCAT[0,352) @ W_F0^T) -> FWRAW @ [352,544) ========
    if (w < 4){
        f32x4 av[2][4]; zacc(av);
        wgemm4<11,2>(av, W+W_F0, 352, ACT, AP, w,r16,g);
        #pragma unroll
        for (int i=0;i<2;++i){
            int n = (w+8*i)*16 + r16;
            #pragma unroll
            for (int mt=0;mt<4;++mt)
                #pragma unroll
                for (int q=0;q<4;++q){
                    int mrow = mt*16+g*4+q;
                    float t = tanh_f(av[i][mt][q]);
                    fwk[i][mt][q] = t;
                    ACT[mrow*AP+352+n] = f2bf(t);
                }
        }
    } else {
        f32x4 av[1][4]; zacc(av);
        wgemm4<11,1>(av, W+W_F0, 352, ACT, AP, w,r16,g);
        int n = w*16 + r16;
        #pragma unroll
        for (int mt=0;mt<4;++mt)
            #pragma unroll
            for (int q=0;q<4;++q){
                int mrow = mt*16+g*4+q;
                float t = tanh_f(av[0][mt][q]);
                fwk[0][mt][q] = t;
                ACT[mrow*AP+352+n] = f2bf(t);
            }
    }
    __syncthreads();

    // ======== f0g GLU: fw*sigm(FWRAW @ W_F0G^T) -> fwc0 @ [0,192) ========
    if (w < 4){
        f32x4 av[2][4]; zacc(av);
        wgemm4<6,2>(av, W+W_F0G, 192, ACT+352, AP, w,r16,g);
        #pragma unroll
        for (int i=0;i<2;++i){
            int n = (w+8*i)*16 + r16;
            #pragma unroll
            for (int mt=0;mt<4;++mt)
                #pragma unroll
                for (int q=0;q<4;++q){
                    int mrow = mt*16+g*4+q;
                    ACT[mrow*AP+n] = f2bf(fwk[i][mt][q]*sigm(av[i][mt][q]));
                }
        }
    } else {
        f32x4 av[1][4]; zacc(av);
        wgemm4<6,1>(av, W+W_F0G, 192, ACT+352, AP, w,r16,g);
        int n = w*16 + r16;
        #pragma unroll
        for (int mt=0;mt<4;++mt)
            #pragma unroll
            for (int q=0;q<4;++q){
                int mrow = mt*16+g*4+q;
                ACT[mrow*AP+n] = f2bf(fwk[0][mt][q]*sigm(av[0][mt][q]));
            }
    }
    __syncthreads();

    // ======== pitch gain: all waves compute tile0 redundantly, wave0 writes ========
    {
        f32x4 av[1][4]; zacc(av);
        wgemm4<6,1>(av, W+W_PG, 192, ACT, AP, 0, r16, g);
        if (w==0 && r16<4){
            float bp = b_pg[r16];
            #pragma unroll
            for (int mt=0;mt<4;++mt)
                #pragma unroll
                for (int q=0;q<4;++q)
                    PGs[mt*16+g*4+q][r16] = sigm(av[0][mt][q] + bp);
        }
    }
    __syncthreads();

    // ======== pf1 @[192,232); prev -> stable slot [232,272) (XCAT dead now) ========
    for (int i=c8;i<40;i+=8){
        ACT[rr*AP+192+i] = f2bf(PGs[rr][0]*bf2f(FPITCHb[rr*40+i]));
        ACT[rr*AP+232+i] = ACT[rr*AP+288+i];
    }
    __syncthreads();

    // ======== GRU1 rz ========
    if (w < 4) gru1_rz<2>(W, ACT, w,r16,g); else gru1_rz<1>(W, ACT, w,r16,g);
    __syncthreads();
    // ======== GRU1 n ========
    float hk1[2][4][4];
    if (w < 4) gru1_n<2>(W, ACT, s1, out, hk1, row0, w,r16,g);
    else       gru1_n<1>(W, ACT, s1, out, hk1, row0, w,r16,g);
    __syncthreads();
    // ======== GLU1 -> g1 @[288,448); stage s2 -> [544,672), pf2@448, prev2@488, z@528 ========
    if (w < 4) glu1<2>(W, ACT, hk1, w,r16,g); else glu1<1>(W, ACT, hk1, w,r16,g);
    for (int i=c8;i<128;i+=8) ACT[rr*AP+544+i] = f2bf(s2[grow*128+i]);
    for (int i=c8;i<40;i+=8){
        ACT[rr*AP+448+i] = f2bf(PGs[rr][1]*bf2f(FPITCHb[rr*40+i]));
        ACT[rr*AP+488+i] = ACT[rr*AP+232+i];     // prev from stable slot
    }
    for (int i=528+c8;i<544;i+=8) ACT[rr*AP+i] = 0;
    __syncthreads();

    // ======== GRU2: x=[288,544) K256, h=[544,672); HB2 -> [768,896) ========
    float hk[4][4];
    gru23_h<8>(W+W_IH2R, W+W_IH2Z, W+W_IH2N, 256,
               W+W_HH2R, W+W_HH2Z, W+W_HH2N,
               ACT+288, ACT+544, s2, out, OH2, ACT+768, hk, row0, w,r16,g);
    __syncthreads();
    // ======== GLU2 -> g2 @[544,672); pf3@672, prev3@712, z@752; s3 -> SH ========
    {
        f32x4 gl[1][4]; zacc(gl);
        wgemm4<4,1>(gl, W+W_GLU2, 128, ACT+768, AP, w,r16,g);
        int n = w*16 + r16;
        #pragma unroll
        for (int mt=0;mt<4;++mt)
            #pragma unroll
            for (int q=0;q<4;++q){
                int mrow = mt*16+g*4+q;
                ACT[mrow*AP+544+n] = f2bf(hk[mt][q]*sigm(gl[0][mt][q]));
            }
    }
    for (int i=c8;i<40;i+=8){
        ACT[rr*AP+672+i] = f2bf(PGs[rr][2]*bf2f(FPITCHb[rr*40+i]));
        ACT[rr*AP+712+i] = ACT[rr*AP+232+i];     // prev from stable slot
    }
    for (int i=752+c8;i<768;i+=8) ACT[rr*AP+i] = 0;
    for (int i=c8;i<128;i+=8) SH[rr*136+i] = f2bf(s3[grow*128+i]);
    __syncthreads();

    // ======== GRU3: x=[544,768) K224, h=SH(pitch 136) — gates in regs ========
    {
        const int n = w*16 + r16;
        float hp[4][4];
        #pragma unroll
        for (int mt=0;mt<4;++mt)
            #pragma unroll
            for (int q=0;q<4;++q)
                hp[mt][q] = s3[(long)(row0+mt*16+g*4+q)*128 + n];
        f32x4 gx[1][4], gh[1][4], ra[1][4], za[1][4];
        zacc(gx); zacc(gh); zacc(ra); zacc(za);
        wgemm4<7,1>(gx, W+W_IH3N, 224, ACT+544, AP, w,r16,g);
        wgemm4<4,1>(gh, W+W_HH3N, 128, SH, 136, w,r16,g);
        wgemm4<7,1>(ra, W+W_IH3R, 224, ACT+544, AP, w,r16,g);
        wgemm4<4,1>(ra, W+W_HH3R, 128, SH, 136, w,r16,g);
        wgemm4<7,1>(za, W+W_IH3Z, 224, ACT+544, AP, w,r16,g);
        wgemm4<4,1>(za, W+W_HH3Z, 128, SH, 136, w,r16,g);
        #pragma unroll
        for (int mt=0;mt<4;++mt)
            #pragma unroll
            for (int q=0;q<4;++q){
                int mrow = mt*16+g*4+q;
                float r = sigm(ra[0][mt][q]), z = sigm(za[0][mt][q]);
                float nn = tanh_f(gx[0][mt][q] + r*gh[0][mt][q]);
                float h = (1.f-z)*nn + z*hp[mt][q];
                out[OH3 + (long)(row0+mrow)*128 + n] = h;
                hk[mt][q] = h;
            }
    }
    __syncthreads();
    // ======== HB3 -> SH (s3 dead) ========
    {
        int n = w*16 + r16;
        #pragma unroll
        for (int mt=0;mt<4;++mt)
            #pragma unroll
            for (int q=0;q<4;++q)
                SH[(mt*16+g*4+q)*136 + n] = f2bf(hk[mt][q]);
    }
    __syncthreads();
    // ======== GLU3 -> g3 @[768,896); pf4@896 ========
    {
        f32x4 gl[1][4]; zacc(gl);
        wgemm4<4,1>(gl, W+W_GLU3, 128, SH, 136, w,r16,g);
        int n = w*16 + r16;
        #pragma unroll
        for (int mt=0;mt<4;++mt)
            #pragma unroll
            for (int q=0;q<4;++q){
                int mrow = mt*16+g*4+q;
                ACT[mrow*AP+768+n] = f2bf(hk[mt][q]*sigm(gl[0][mt][q]));
            }
    }
    for (int i=c8;i<40;i+=8)
        ACT[rr*AP+896+i] = f2bf(PGs[rr][3]*bf2f(FPITCHb[rr*40+i]));
    __syncthreads();

    // ======== skip: tanh(ACT[0,960) @ W_SKIP^T) -> SK @ SH ========
    float skk[4][4];
    {
        f32x4 av[1][4]; zacc(av);
        wgemm4<30,1>(av, W+W_SKIP, 960, ACT, AP, w,r16,g);
        int n = w*16 + r16;
        #pragma unroll
        for (int mt=0;mt<4;++mt)
            #pragma unroll
            for (int q=0;q<4;++q){
                int mrow = mt*16+g*4+q;
                float t = tanh_f(av[0][mt][q]);
                skk[mt][q] = t;
                SH[mrow*136+n] = f2bf(t);
            }
    }
    __syncthreads();
    // ======== skip GLU -> SK2 @ ACT[0,128) ========
    {
        f32x4 av[1][4]; zacc(av);
        wgemm4<4,1>(av, W+W_SKIPG, 128, SH, 136, w,r16,g);
        int n = w*16 + r16;
        #pragma unroll
        for (int mt=0;mt<4;++mt)
            #pragma unroll
            for (int q=0;q<4;++q){
                int mrow = mt*16+g*4+q;
                ACT[mrow*AP+n] = f2bf(skk[mt][q]*sigm(av[0][mt][q]));
            }
    }
    __syncthreads();
    // ======== sig: waves 0-3 (Npad=64), valid n<40 ========
    if (w < 4){
        f32x4 av[1][4]; zacc(av);
        wgemm4<4,1>(av, W+W_SIG, 128, ACT, AP, w,r16,g);
        int n = w*16 + r16;
        if (n < 40){
            #pragma unroll
            for (int mt=0;mt<4;++mt)
                #pragma unroll
                for (int q=0;q<4;++q){
                    int mrow = mt*16+g*4+q;
                    float sv = tanh_f(av[0][mt][q]) * GAIN[mrow];
                    out[OSIG + (long)(row0+mrow)*40 + n] = sv;
                    out[OEXC + (long)(row0+mrow)*256 + 216 + n] = sv;
                }
        }
    }
}

extern "C" void kernel_launch(void* const* d_in, const int* in_sizes, int n_in,
                              void* d_out, int out_size, void* d_ws, size_t ws_size,
                              hipStream_t stream) {
    const float* cond      = (const float*)d_in[0];
    const float* prev_pred = (const float*)d_in[1];
    const float* exc_mem   = (const float*)d_in[2];
    const float* period    = (const float*)d_in[3];
    const float* s1        = (const float*)d_in[4];
    const float* s2        = (const float*)d_in[5];
    const float* s3        = (const float*)d_in[6];
    const float* s4        = (const float*)d_in[7];
    const float* w_gain    = (const float*)d_in[8];
    const float* b_gain    = (const float*)d_in[9];
    const float* w_fwc0    = (const float*)d_in[10];
    const float* w_fwc0_glu= (const float*)d_in[11];
    const float* wih1      = (const float*)d_in[12];
    const float* whh1      = (const float*)d_in[13];
    const float* wglu1     = (const float*)d_in[14];
    const float* wih2      = (const float*)d_in[15];
    const float* whh2      = (const float*)d_in[16];
    const float* wglu2     = (const float*)d_in[17];
    const float* wih3      = (const float*)d_in[18];
    const float* whh3      = (const float*)d_in[19];
    const float* wglu3     = (const float*)d_in[20];
    const float* w_skip    = (const float*)d_in[21];
    const float* w_skip_glu= (const float*)d_in[22];
    const float* w_sig     = (const float*)d_in[23];
    const float* w_pg      = (const float*)d_in[24];
    const float* b_pg      = (const float*)d_in[25];
    float* out = (float*)d_out;
    uint16_t* wsbf = (uint16_t*)d_ws;

    PrepArgs pa;
    pa.s[0]=w_fwc0; pa.s[1]=w_fwc0_glu; pa.s[2]=wih1; pa.s[3]=whh1; pa.s[4]=wglu1;
    pa.s[5]=wih2; pa.s[6]=whh2; pa.s[7]=wglu2; pa.s[8]=wih3; pa.s[9]=whh3;
    pa.s[10]=wglu3; pa.s[11]=w_skip; pa.s[12]=w_skip_glu; pa.s[13]=w_pg; pa.s[14]=w_sig;

    hipLaunchKernelGGL(prep_kernel, dim3(3856), dim3(64), 0, stream, pa, wsbf);
    hipLaunchKernelGGL(fargan_mfma, dim3(512), dim3(512), 0, stream,
        cond, prev_pred, exc_mem, period, s1, s2, s3, s4,
        w_gain, b_gain, b_pg, wsbf, out);
}

// Round 10
// 227.691 us; speedup vs baseline: 32.9929x; 1.2837x over previous
//
#include <hip/hip_runtime.h>
#include <cstdint>
#include <cmath>

#define BTOT 32768L
#define OSIG 0L
#define OEXC (BTOT*40L)
#define OPREV (OEXC + BTOT*256L)
#define OH1 (OPREV + BTOT*256L)
#define OH2 (OH1 + BTOT*160L)
#define OH3 (OH2 + BTOT*128L)
#define ONS4 (OH3 + BTOT*128L)

typedef __attribute__((ext_vector_type(8))) short short8;
typedef __attribute__((ext_vector_type(4))) short short4v;
typedef __attribute__((ext_vector_type(4))) float f32x4;

#define AP 968   // ACT pitch (bf16 elems)

// ACT column map (lifetime-multiplexed):
//  [0,192)   XCAT s4[0,164)/cond[164,244) -> fwc0 (after f0g) -> SK2 (after skipg)
//  [192,232) pf1          [232,272) prev stable slot (written pf1 phase)
//  [244,288) XCAT pred_n (dead after fwc0)
//  [288,328) XCAT prev src -> g1 [288,448)  (LIVE until skip!)
//  [328,352) zeros (XCAT pad)
//  [352,544) FWRAW (dead after f0g; [352,448) then owned by g1)
//  [448,488) pf2, [488,528) prev2, [528,544) zeros
//  [544,736) s1-state -> s2 [544,672) -> g2 [544,672); [672,712) pf3, [712,752) prev3, [752,768) zeros
//  [768,960) HB1 -> HB2 [768,896) -> g3 [768,896), pf4 [896,936), HB1-zero tail [936,960)
// SH (pitch 136): s3-state -> HB3 -> SK

// ws layout (bf16). All blocks [Npad][KP], row-major, zero-padded.
#define W_F0     0L        // [192][352]
#define W_F0G    67584L    // [192][192]
#define W_PG     104448L   // [16][192]
#define W_IH1R   107520L   // [192][288]
#define W_IH1Z   162816L
#define W_IH1N   218112L
#define W_HH1R   273408L   // [192][192]
#define W_HH1Z   310272L
#define W_HH1N   347136L
#define W_GLU1   384000L   // [192][192]
#define W_IH2R   420864L   // [128][256]
#define W_IH2Z   453632L
#define W_IH2N   486400L
#define W_HH2R   519168L   // [128][128]
#define W_HH2Z   535552L
#define W_HH2N   551936L
#define W_GLU2   568320L   // [128][128]
#define W_IH3R   584704L   // [128][224]
#define W_IH3Z   613376L
#define W_IH3N   642048L
#define W_HH3R   670720L   // [128][128]
#define W_HH3Z   687104L
#define W_HH3N   703488L
#define W_GLU3   719872L   // [128][128]
#define W_SKIP   736256L   // [128][960] column-permuted to ACT map
#define W_SKIPG  859136L   // [128][128]
#define W_SIG    875520L   // [64][128]

__device__ __forceinline__ float sigm(float x){ return 1.0f/(1.0f+__expf(-x)); }
__device__ __forceinline__ float tanh_f(float x){
    float e = __expf(2.0f*x);
    return 1.0f - 2.0f/(e+1.0f);
}
__device__ __forceinline__ uint16_t f2bf(float x){
    union { float f; uint32_t u; } v; v.f = x;
    uint32_t r = v.u + 0x7FFFu + ((v.u>>16)&1u);
    return (uint16_t)(r>>16);
}
__device__ __forceinline__ float bf2f(uint16_t h){
    union { float f; uint32_t u; } v; v.u = ((uint32_t)h)<<16;
    return v.f;
}
__device__ __forceinline__ short4v pack4(float4 v){
    short4v r;
    r.x=(short)f2bf(v.x); r.y=(short)f2bf(v.y); r.z=(short)f2bf(v.z); r.w=(short)f2bf(v.w);
    return r;
}

// ---------------- prep: fp32 weights -> padded bf16 blocks in ws ----------------
struct PrepArgs { const float* s[15]; };

__global__ __launch_bounds__(64) void prep_kernel(PrepArgs pa, uint16_t* dst){
    static const long J[27][8] = {
        {0,  0,192,328,352,192, W_F0,   0},
        {1,  0,192,192,192,192, W_F0G,  0},
        {13, 0,  4,192,192, 16, W_PG,   0},
        {2,  0,160,272,288,192, W_IH1R, 0},
        {2,160,160,272,288,192, W_IH1Z, 0},
        {2,320,160,272,288,192, W_IH1N, 0},
        {3,  0,160,160,192,192, W_HH1R, 0},
        {3,160,160,160,192,192, W_HH1Z, 0},
        {3,320,160,160,192,192, W_HH1N, 0},
        {4,  0,160,160,192,192, W_GLU1, 0},
        {5,  0,128,240,256,128, W_IH2R, 0},
        {5,128,128,240,256,128, W_IH2Z, 0},
        {5,256,128,240,256,128, W_IH2N, 0},
        {6,  0,128,128,128,128, W_HH2R, 0},
        {6,128,128,128,128,128, W_HH2Z, 0},
        {6,256,128,128,128,128, W_HH2N, 0},
        {7,  0,128,128,128,128, W_GLU2, 0},
        {8,  0,128,208,224,128, W_IH3R, 0},
        {8,128,128,208,224,128, W_IH3Z, 0},
        {8,256,128,208,224,128, W_IH3N, 0},
        {9,  0,128,128,128,128, W_HH3R, 0},
        {9,128,128,128,128,128, W_HH3Z, 0},
        {9,256,128,128,128,128, W_HH3N, 0},
        {10, 0,128,128,128,128, W_GLU3, 0},
        {11, 0,128,688,960,128, W_SKIP, 1},
        {12, 0,128,128,128,128, W_SKIPG,0},
        {14, 0, 40,128,128, 64, W_SIG,  0},
    };
    long row = blockIdx.x;
    int j = 0;
    while (row >= J[j][5]) { row -= J[j][5]; ++j; }
    const float* src = pa.s[J[j][0]];
    const long ro = J[j][1], N = J[j][2], K = J[j][3], KP = J[j][4];
    const int type = (int)J[j][7];
    uint16_t* d = dst + J[j][6] + row*KP;
    for (long k = threadIdx.x; k < KP; k += 64){
        float v = 0.0f;
        if (row < N){
            if (type == 0){
                if (k < K) v = src[(ro+row)*K + k];
            } else {
                long s = -1;
                if (k < 192) s = 416 + k;                        // fwc0
                else if (k >= 232 && k < 272) s = 648 + (k-232); // prev
                else if (k >= 288 && k < 448) s = (k-288);       // g1
                else if (k >= 544 && k < 672) s = 160 + (k-544); // g2
                else if (k >= 768 && k < 896) s = 288 + (k-768); // g3
                else if (k >= 896 && k < 936) s = 608 + (k-896); // pf4
                if (s >= 0) v = src[row*688 + s];
            }
        }
        d[k] = f2bf(v);
    }
}

// ---------------- quad-m-tile wave GEMM with 6-deep B-load ring prefetch ----------------
template<int KS, int CNT>
__device__ __forceinline__ void wgemm4(f32x4 (&acc)[CNT][4],
    const uint16_t* __restrict__ Bw, int KP,
    const uint16_t* A, int P, int w, int r16, int g)
{
    constexpr int T = KS*CNT;
    constexpr int PF = (T < 6) ? T : 6;
    const uint16_t* ap = A + r16*P + g*8;
    const uint16_t* bbase = Bw + (size_t)(w*16 + r16)*KP + g*8;
    short8 ring[PF];
    #pragma unroll
    for (int t=0;t<PF;++t)
        ring[t] = *(const short8*)(bbase + (size_t)(t%CNT)*128*KP + (size_t)(t/CNT)*32);
    short8 af[4];
    #pragma unroll
    for (int t=0;t<T;++t){
        const int s = t/CNT, i = t%CNT;
        if (i==0){
            #pragma unroll
            for (int mt=0;mt<4;++mt) af[mt] = *(const short8*)(ap + mt*16*P + s*32);
        }
        short8 bf = ring[t%PF];
        if (t+PF < T)
            ring[t%PF] = *(const short8*)(bbase + (size_t)((t+PF)%CNT)*128*KP + (size_t)((t+PF)/CNT)*32);
        #pragma unroll
        for (int mt=0;mt<4;++mt)
            acc[i][mt] = __builtin_amdgcn_mfma_f32_16x16x32_bf16(af[mt], bf, acc[i][mt],0,0,0);
    }
}
template<int CNT> __device__ __forceinline__ void zacc(f32x4 (&a)[CNT][4]){
    f32x4 z4 = {0.f,0.f,0.f,0.f};
    #pragma unroll
    for (int i=0;i<CNT;++i){
        #pragma unroll
        for (int mt=0;mt<4;++mt) a[i][mt]=z4;
    }
}

// ---------------- GRU1 merged h-phase (H=160, x=[0,288) K288, h=[544,736) K192) ----------------
template<int CNT>
__device__ __forceinline__ void gru1_h(const uint16_t* __restrict__ W, uint16_t* ACTp,
    const float* __restrict__ s1g, float* __restrict__ out,
    float (&hk)[2][4][4], int row0, int w, int r16, int g)
{
    f32x4 gx[CNT][4], gh[CNT][4], ra[CNT][4], za[CNT][4];
    zacc(gx); zacc(gh); zacc(ra); zacc(za);
    wgemm4<9,CNT>(gx, W+W_IH1N, 288, ACTp,     AP, w,r16,g);
    wgemm4<9,CNT>(ra, W+W_IH1R, 288, ACTp,     AP, w,r16,g);
    wgemm4<9,CNT>(za, W+W_IH1Z, 288, ACTp,     AP, w,r16,g);
    wgemm4<6,CNT>(gh, W+W_HH1N, 192, ACTp+544, AP, w,r16,g);
    wgemm4<6,CNT>(ra, W+W_HH1R, 192, ACTp+544, AP, w,r16,g);
    wgemm4<6,CNT>(za, W+W_HH1Z, 192, ACTp+544, AP, w,r16,g);
    #pragma unroll
    for (int i=0;i<CNT;++i){
        int n = (w+8*i)*16 + r16;
        #pragma unroll
        for (int mt=0;mt<4;++mt){
            #pragma unroll
            for (int q=0;q<4;++q){
                int mrow = mt*16+g*4+q;
                float h = 0.f;
                if (n < 160){
                    float hpv = s1g[(long)(row0+mrow)*160 + n];
                    float r = sigm(ra[i][mt][q]);
                    float z = sigm(za[i][mt][q]);
                    float nn = tanh_f(gx[i][mt][q] + r*gh[i][mt][q]);
                    h = (1.f-z)*nn + z*hpv;
                    out[OH1 + (long)(row0+mrow)*160 + n] = h;
                }
                hk[i][mt][q] = h;
                ACTp[mrow*AP+768+n] = f2bf(h);   // HB1 (h; zeros n>=160)
            }
        }
    }
}
template<int CNT>
__device__ __forceinline__ void glu1(const uint16_t* __restrict__ W, uint16_t* ACTp,
                                     float (&hk)[2][4][4], int w, int r16, int g){
    f32x4 gl[CNT][4];
    zacc(gl);
    wgemm4<6,CNT>(gl, W+W_GLU1, 192, ACTp+768, AP, w,r16,g);
    #pragma unroll
    for (int i=0;i<CNT;++i){
        int n = (w+8*i)*16 + r16;
        if (n < 160){
            #pragma unroll
            for (int mt=0;mt<4;++mt)
                #pragma unroll
                for (int q=0;q<4;++q){
                    int mrow = mt*16+g*4+q;
                    ACTp[mrow*AP + 288 + n] = f2bf(hk[i][mt][q]*sigm(gl[i][mt][q]));  // g1
                }
        }
    }
}

// ---------------- GRU2/3 merged h-phase (H=128) ----------------
template<int KSX, int KSH>
__device__ __forceinline__ void gru23_h(
    const uint16_t* __restrict__ Wxr, const uint16_t* __restrict__ Wxz, const uint16_t* __restrict__ Wxn, int KPX,
    const uint16_t* __restrict__ Whr, const uint16_t* __restrict__ Whz, const uint16_t* __restrict__ Whn, int KPH,
    const uint16_t* XA, const uint16_t* HA, int HAP,
    const float* __restrict__ sg, float* __restrict__ outp, long obase,
    uint16_t* HBdst, int HBpitch,
    float (&hk)[4][4], int row0, int w, int r16, int g)
{
    const int n = w*16 + r16;
    f32x4 gx[1][4], gh[1][4], ra[1][4], za[1][4];
    zacc(gx); zacc(gh); zacc(ra); zacc(za);
    wgemm4<KSX,1>(gx, Wxn, KPX, XA, AP, w,r16,g);
    wgemm4<KSX,1>(ra, Wxr, KPX, XA, AP, w,r16,g);
    wgemm4<KSX,1>(za, Wxz, KPX, XA, AP, w,r16,g);
    wgemm4<KSH,1>(gh, Whn, KPH, HA, HAP, w,r16,g);
    wgemm4<KSH,1>(ra, Whr, KPH, HA, HAP, w,r16,g);
    wgemm4<KSH,1>(za, Whz, KPH, HA, HAP, w,r16,g);
    #pragma unroll
    for (int mt=0;mt<4;++mt){
        #pragma unroll
        for (int q=0;q<4;++q){
            int mrow = mt*16+g*4+q;
            float hpv = sg[(long)(row0+mrow)*128 + n];
            float r = sigm(ra[0][mt][q]), z = sigm(za[0][mt][q]);
            float nn = tanh_f(gx[0][mt][q] + r*gh[0][mt][q]);
            float h = (1.f-z)*nn + z*hpv;
            outp[obase + (long)(row0+mrow)*128 + n] = h;
            hk[mt][q] = h;
            if (HBdst) HBdst[mrow*HBpitch + n] = f2bf(h);
        }
    }
}

// ---------------- main kernel: 64 rows / block, 512 threads, 1 block/CU ----------------
extern "C" __global__ __launch_bounds__(512, 2)
void fargan_mfma(const float* __restrict__ cond, const float* __restrict__ prev_pred,
                 const float* __restrict__ exc_mem, const float* __restrict__ period,
                 const float* __restrict__ s1, const float* __restrict__ s2,
                 const float* __restrict__ s3, const float* __restrict__ s4,
                 const float* __restrict__ w_gain, const float* __restrict__ b_gain,
                 const float* __restrict__ b_pg,
                 const uint16_t* __restrict__ W, float* __restrict__ out)
{
    __shared__ __align__(16) uint16_t ACT[64*AP];
    __shared__ __align__(16) uint16_t SH[64*136];
    __shared__ uint16_t FPITCHb[64*40];
    __shared__ float GAIN[64];
    __shared__ float PGs[64][4];

    const int tid = threadIdx.x;
    const int row0 = blockIdx.x * 64;
    const int w = tid >> 6, l = tid & 63, r16 = l & 15, g = l >> 4;
    const int rr = tid >> 3, c8 = tid & 7;
    const long grow = row0 + rr;

    // ======== stage A (float4-vectorized) ========
    const float* exc_row = exc_mem + grow*256;

    float a0 = 0.f;
    {
        const float4* c4 = (const float4*)(cond + grow*80);
        const float4* g4 = (const float4*)w_gain;
        float4* on4 = (float4*)(out + ONS4 + grow*164);
        for (int i=c8;i<20;i+=8){
            float4 cv = c4[i], gv = g4[i];
            a0 += cv.x*gv.x + cv.y*gv.y + cv.z*gv.z + cv.w*gv.w;
            *(short4v*)&ACT[rr*AP + 164 + 4*i] = pack4(cv);
            on4[i] = cv;
        }
    }
    a0 += __shfl_xor(a0,4,8); a0 += __shfl_xor(a0,2,8); a0 += __shfl_xor(a0,1,8);
    float gn = 0.2f + 0.8f*sigm(a0 + b_gain[0]);
    if (!(gn==gn)) gn = 1.0f;
    gn = fminf(fmaxf(gn, 0.001f), 20.0f);
    float inv = 1.0f/(1e-5f+gn);
    if (c8==0) GAIN[rr] = gn;

    float p = period[grow];
    p = (fabsf(p) <= 3.0e38f) ? p : 128.0f;
    p = fminf(fmaxf(p, 32.0f), 255.0f);

    for (int e=c8;e<44;e+=8){
        float idxf = 254.0f - p + (float)e;
        float idx0 = floorf(idxf);
        float al = fminf(fmaxf(idxf-idx0, 0.f), 1.f);
        int i0 = (int)fminf(fmaxf(idx0, 0.f), 255.f);
        int i1 = (int)fminf(fmaxf(idx0+1.f, 0.f), 255.f);
        float pr = (1.f-al)*exc_row[i0] + al*exc_row[i1];
        float pn = pr*inv;
        ACT[rr*AP + 244 + e] = f2bf(pn);             // XCAT pred_n
        out[ONS4 + grow*164 + 80 + e] = pn;
        if (e>=2 && e<42){
            out[OPREV + grow*256 + 216 + (e-2)] = pr;
            FPITCHb[rr*40 + (e-2)] = f2bf(pn);
        }
    }
    {
        const float4* pv4 = (const float4*)(exc_row + 216);
        float4* onp = (float4*)(out + ONS4 + grow*164 + 124);
        for (int i=c8;i<10;i+=8){
            float4 v = pv4[i];
            v.x*=inv; v.y*=inv; v.z*=inv; v.w*=inv;
            *(short4v*)&ACT[rr*AP + 288 + 4*i] = pack4(v);   // XCAT prev (stable until GLU1)
            onp[i] = v;
        }
    }
    {
        const float4* s44 = (const float4*)(s4 + grow*164);
        for (int i=c8;i<41;i+=8)
            *(short4v*)&ACT[rr*AP + 4*i] = pack4(s44[i]);    // XCAT s4
        const float4* s14 = (const float4*)(s1 + grow*160);
        for (int i=c8;i<40;i+=8)
            *(short4v*)&ACT[rr*AP + 544 + 4*i] = pack4(s14[i]);  // s1-state
    }
    for (int i=328+c8;i<352;i+=8) ACT[rr*AP + i] = 0;            // XCAT pad
    for (int i=704+c8;i<736;i+=8) ACT[rr*AP + i] = 0;            // s1 pad
    {
        const float4* pp4 = (const float4*)(prev_pred + grow*256 + 40);
        const float4* ex4 = (const float4*)(exc_row + 40);
        float4* op4 = (float4*)(out + OPREV + grow*256);
        float4* oe4 = (float4*)(out + OEXC + grow*256);
        for (int i=c8;i<54;i+=8){ op4[i] = pp4[i]; oe4[i] = ex4[i]; }
    }
    __syncthreads();

    float fwk[2][4][4];

    // ======== fwc0: tanh(XCAT[0,352) @ W_F0^T) -> FWRAW @ [352,544) ========
    if (w < 4){
        f32x4 av[2][4]; zacc(av);
        wgemm4<11,2>(av, W+W_F0, 352, ACT, AP, w,r16,g);
        #pragma unroll
        for (int i=0;i<2;++i){
            int n = (w+8*i)*16 + r16;
            #pragma unroll
            for (int mt=0;mt<4;++mt)
                #pragma unroll
                for (int q=0;q<4;++q){
                    int mrow = mt*16+g*4+q;
                    float t = tanh_f(av[i][mt][q]);
                    fwk[i][mt][q] = t;
                    ACT[mrow*AP+352+n] = f2bf(t);
                }
        }
    } else {
        f32x4 av[1][4]; zacc(av);
        wgemm4<11,1>(av, W+W_F0, 352, ACT, AP, w,r16,g);
        int n = w*16 + r16;
        #pragma unroll
        for (int mt=0;mt<4;++mt)
            #pragma unroll
            for (int q=0;q<4;++q){
                int mrow = mt*16+g*4+q;
                float t = tanh_f(av[0][mt][q]);
                fwk[0][mt][q] = t;
                ACT[mrow*AP+352+n] = f2bf(t);
            }
    }
    __syncthreads();

    // ======== f0g GLU -> fwc0 @ [0,192) ========
    if (w < 4){
        f32x4 av[2][4]; zacc(av);
        wgemm4<6,2>(av, W+W_F0G, 192, ACT+352, AP, w,r16,g);
        #pragma unroll
        for (int i=0;i<2;++i){
            int n = (w+8*i)*16 + r16;
            #pragma unroll
            for (int mt=0;mt<4;++mt)
                #pragma unroll
                for (int q=0;q<4;++q){
                    int mrow = mt*16+g*4+q;
                    ACT[mrow*AP+n] = f2bf(fwk[i][mt][q]*sigm(av[i][mt][q]));
                }
        }
    } else {
        f32x4 av[1][4]; zacc(av);
        wgemm4<6,1>(av, W+W_F0G, 192, ACT+352, AP, w,r16,g);
        int n = w*16 + r16;
        #pragma unroll
        for (int mt=0;mt<4;++mt)
            #pragma unroll
            for (int q=0;q<4;++q){
                int mrow = mt*16+g*4+q;
                ACT[mrow*AP+n] = f2bf(fwk[0][mt][q]*sigm(av[0][mt][q]));
            }
    }
    __syncthreads();

    // ======== pitch gain (redundant per wave; wave0 writes) ========
    {
        f32x4 av[1][4]; zacc(av);
        wgemm4<6,1>(av, W+W_PG, 192, ACT, AP, 0, r16, g);
        if (w==0 && r16<4){
            float bp = b_pg[r16];
            #pragma unroll
            for (int mt=0;mt<4;++mt)
                #pragma unroll
                for (int q=0;q<4;++q)
                    PGs[mt*16+g*4+q][r16] = sigm(av[0][mt][q] + bp);
        }
    }
    __syncthreads();

    // ======== pf1 @[192,232); prev -> stable [232,272) ========
    for (int i=c8;i<40;i+=8){
        ACT[rr*AP+192+i] = f2bf(PGs[rr][0]*bf2f(FPITCHb[rr*40+i]));
        ACT[rr*AP+232+i] = ACT[rr*AP+288+i];
    }
    __syncthreads();

    // ======== GRU1 merged h-phase ========
    float hk1[2][4][4];
    if (w < 4) gru1_h<2>(W, ACT, s1, out, hk1, row0, w,r16,g);
    else       gru1_h<1>(W, ACT, s1, out, hk1, row0, w,r16,g);
    __syncthreads();

    // ======== GLU1 -> g1 @[288,448); stage s2 -> [544,672), pf2@448, prev2@488, z@528 ========
    if (w < 4) glu1<2>(W, ACT, hk1, w,r16,g); else glu1<1>(W, ACT, hk1, w,r16,g);
    {
        const float4* s24 = (const float4*)(s2 + grow*128);
        for (int i=c8;i<32;i+=8)
            *(short4v*)&ACT[rr*AP + 544 + 4*i] = pack4(s24[i]);
    }
    for (int i=c8;i<40;i+=8){
        ACT[rr*AP+448+i] = f2bf(PGs[rr][1]*bf2f(FPITCHb[rr*40+i]));
        ACT[rr*AP+488+i] = ACT[rr*AP+232+i];
    }
    for (int i=528+c8;i<544;i+=8) ACT[rr*AP+i] = 0;
    __syncthreads();

    // ======== GRU2: x=[288,544) K256, h=[544,672); HB2 -> [768,896) ========
    float hk[4][4];
    gru23_h<8,4>(W+W_IH2R, W+W_IH2Z, W+W_IH2N, 256,
                 W+W_HH2R, W+W_HH2Z, W+W_HH2N, 128,
                 ACT+288, ACT+544, AP, s2, out, OH2,
                 ACT+768, AP, hk, row0, w,r16,g);
    __syncthreads();

    // ======== GLU2 -> g2 @[544,672); stage s3 -> SH, pf3@672, prev3@712, z@752 ========
    {
        f32x4 gl[1][4]; zacc(gl);
        wgemm4<4,1>(gl, W+W_GLU2, 128, ACT+768, AP, w,r16,g);
        int n = w*16 + r16;
        #pragma unroll
        for (int mt=0;mt<4;++mt)
            #pragma unroll
            for (int q=0;q<4;++q){
                int mrow = mt*16+g*4+q;
                ACT[mrow*AP+544+n] = f2bf(hk[mt][q]*sigm(gl[0][mt][q]));
            }
    }
    {
        const float4* s34 = (const float4*)(s3 + grow*128);
        for (int i=c8;i<32;i+=8)
            *(short4v*)&SH[rr*136 + 4*i] = pack4(s34[i]);
    }
    for (int i=c8;i<40;i+=8){
        ACT[rr*AP+672+i] = f2bf(PGs[rr][2]*bf2f(FPITCHb[rr*40+i]));
        ACT[rr*AP+712+i] = ACT[rr*AP+232+i];
    }
    for (int i=752+c8;i<768;i+=8) ACT[rr*AP+i] = 0;
    __syncthreads();

    // ======== GRU3: x=[544,768) K224, h=SH (pitch 136); hk kept in regs ========
    gru23_h<7,4>(W+W_IH3R, W+W_IH3Z, W+W_IH3N, 224,
                 W+W_HH3R, W+W_HH3Z, W+W_HH3N, 128,
                 ACT+544, SH, 136, s3, out, OH3,
                 (uint16_t*)nullptr, 0, hk, row0, w,r16,g);
    __syncthreads();

    // ======== HB3 -> SH (s3 dead) ========
    {
        int n = w*16 + r16;
        #pragma unroll
        for (int mt=0;mt<4;++mt)
            #pragma unroll
            for (int q=0;q<4;++q)
                SH[(mt*16+g*4+q)*136 + n] = f2bf(hk[mt][q]);
    }
    __syncthreads();

    // ======== GLU3 (reads SH, pitch 136) -> g3 @[768,896); pf4@896 ========
    {
        f32x4 gl[1][4]; zacc(gl);
        {
            const uint16_t* ap = SH + r16*136 + g*8;
            const uint16_t* bbase = W + W_GLU3 + (size_t)(w*16 + r16)*128 + g*8;
            short8 ring[4];
            #pragma unroll
            for (int t=0;t<4;++t) ring[t] = *(const short8*)(bbase + t*32);
            #pragma unroll
            for (int s=0;s<4;++s){
                short8 af[4];
                #pragma unroll
                for (int mt=0;mt<4;++mt) af[mt] = *(const short8*)(ap + mt*16*136 + s*32);
                short8 bf = ring[s];
                #pragma unroll
                for (int mt=0;mt<4;++mt)
                    gl[0][mt] = __builtin_amdgcn_mfma_f32_16x16x32_bf16(af[mt], bf, gl[0][mt],0,0,0);
            }
        }
        int n = w*16 + r16;
        #pragma unroll
        for (int mt=0;mt<4;++mt)
            #pragma unroll
            for (int q=0;q<4;++q){
                int mrow = mt*16+g*4+q;
                ACT[mrow*AP+768+n] = f2bf(hk[mt][q]*sigm(gl[0][mt][q]));
            }
    }
    for (int i=c8;i<40;i+=8)
        ACT[rr*AP+896+i] = f2bf(PGs[rr][3]*bf2f(FPITCHb[rr*40+i]));
    __syncthreads();

    // ======== skip: tanh(ACT[0,960) @ W_SKIP^T) -> SK @ SH ========
    float skk[4][4];
    {
        f32x4 av[1][4]; zacc(av);
        wgemm4<30,1>(av, W+W_SKIP, 960, ACT, AP, w,r16,g);
        int n = w*16 + r16;
        #pragma unroll
        for (int mt=0;mt<4;++mt)
            #pragma unroll
            for (int q=0;q<4;++q){
                int mrow = mt*16+g*4+q;
                float t = tanh_f(av[0][mt][q]);
                skk[mt][q] = t;
                SH[mrow*136+n] = f2bf(t);
            }
    }
    __syncthreads();
    // ======== skip GLU (reads SH, pitch 136) -> SK2 @ ACT[0,128) ========
    {
        f32x4 av[1][4]; zacc(av);
        {
            const uint16_t* ap = SH + r16*136 + g*8;
            const uint16_t* bbase = W + W_SKIPG + (size_t)(w*16 + r16)*128 + g*8;
            short8 ring[4];
            #pragma unroll
            for (int t=0;t<4;++t) ring[t] = *(const short8*)(bbase + t*32);
            #pragma unroll
            for (int s=0;s<4;++s){
                short8 af[4];
                #pragma unroll
                for (int mt=0;mt<4;++mt) af[mt] = *(const short8*)(ap + mt*16*136 + s*32);
                short8 bf = ring[s];
                #pragma unroll
                for (int mt=0;mt<4;++mt)
                    av[0][mt] = __builtin_amdgcn_mfma_f32_16x16x32_bf16(af[mt], bf, av[0][mt],0,0,0);
            }
        }
        int n = w*16 + r16;
        #pragma unroll
        for (int mt=0;mt<4;++mt)
            #pragma unroll
            for (int q=0;q<4;++q){
                int mrow = mt*16+g*4+q;
                ACT[mrow*AP+n] = f2bf(skk[mt][q]*sigm(av[0][mt][q]));
            }
    }
    __syncthreads();
    // ======== sig: waves 0-3 (Npad=64), valid n<40 ========
    if (w < 4){
        f32x4 av[1][4]; zacc(av);
        wgemm4<4,1>(av, W+W_SIG, 128, ACT, AP, w,r16,g);
        int n = w*16 + r16;
        if (n < 40){
            #pragma unroll
            for (int mt=0;mt<4;++mt)
                #pragma unroll
                for (int q=0;q<4;++q){
                    int mrow = mt*16+g*4+q;
                    float sv = tanh_f(av[0][mt][q]) * GAIN[mrow];
                    out[OSIG + (long)(row0+mrow)*40 + n] = sv;
                    out[OEXC + (long)(row0+mrow)*256 + 216 + n] = sv;
                }
        }
    }
}

extern "C" void kernel_launch(void* const* d_in, const int* in_sizes, int n_in,
                              void* d_out, int out_size, void* d_ws, size_t ws_size,
                              hipStream_t stream) {
    const float* cond      = (const float*)d_in[0];
    const float* prev_pred = (const float*)d_in[1];
    const float* exc_mem   = (const float*)d_in[2];
    const float* period    = (const float*)d_in[3];
    const float* s1        = (const float*)d_in[4];
    const float* s2        = (const float*)d_in[5];
    const float* s3        = (const float*)d_in[6];
    const float* s4        = (const float*)d_in[7];
    const float* w_gain    = (const float*)d_in[8];
    const float* b_gain    = (const float*)d_in[9];
    const float* w_fwc0    = (const float*)d_in[10];
    const float* w_fwc0_glu= (const float*)d_in[11];
    const float* wih1      = (const float*)d_in[12];
    const float* whh1      = (const float*)d_in[13];
    const float* wglu1     = (const float*)d_in[14];
    const float* wih2      = (const float*)d_in[15];
    const float* whh2      = (const float*)d_in[16];
    const float* wglu2     = (const float*)d_in[17];
    const float* wih3      = (const float*)d_in[18];
    const float* whh3      = (const float*)d_in[19];
    const float* wglu3     = (const float*)d_in[20];
    const float* w_skip    = (const float*)d_in[21];
    const float* w_skip_glu= (const float*)d_in[22];
    const float* w_sig     = (const float*)d_in[23];
    const float* w_pg      = (const float*)d_in[24];
    const float* b_pg      = (const float*)d_in[25];
    float* out = (float*)d_out;
    uint16_t* wsbf = (uint16_t*)d_ws;

    PrepArgs pa;
    pa.s[0]=w_fwc0; pa.s[1]=w_fwc0_glu; pa.s[2]=wih1; pa.s[3]=whh1; pa.s[4]=wglu1;
    pa.s[5]=wih2; pa.s[6]=whh2; pa.s[7]=wglu2; pa.s[8]=wih3; pa.s[9]=whh3;
    pa.s[10]=wglu3; pa.s[11]=w_skip; pa.s[12]=w_skip_glu; pa.s[13]=w_pg; pa.s[14]=w_sig;

    hipLaunchKernelGGL(prep_kernel, dim3(3856), dim3(64), 0, stream, pa, wsbf);
    hipLaunchKernelGGL(fargan_mfma, dim3(512), dim3(512), 0, stream,
        cond, prev_pred, exc_mem, period, s1, s2, s3, s4,
        w_gain, b_gain, b_pg, wsbf, out);
}